// Round 1
// baseline (212.322 us; speedup 1.0000x reference)
//
#include <hip/hip_runtime.h>
#include <hip/hip_fp16.h>

typedef _Float16 __attribute__((ext_vector_type(8))) f16x8;
typedef float __attribute__((ext_vector_type(4))) f32x4;

#define MFMA16(a, b, c) __builtin_amdgcn_mfma_f32_16x16x32_f16(a, b, c, 0, 0, 0)

// ---------------------------------------------------------------- prep weights
__global__ __launch_bounds__(256) void prep_w_kernel(
    const float* __restrict__ Wq, const float* __restrict__ Wk,
    const float* __restrict__ Wv, const float* __restrict__ Wp,
    _Float16* __restrict__ out)
{
    int i = blockIdx.x * 256 + threadIdx.x;   // 262144 total
    int w = i >> 16, j = i & 65535;
    const float* src = (w == 0) ? Wq : (w == 1) ? Wk : (w == 2) ? Wv : Wp;
    out[i] = (_Float16)src[j];
}

// ---------------------------------------------------------------- BN stats
__global__ __launch_bounds__(256) void bn_stats_kernel(
    const float* __restrict__ x, const float* __restrict__ gamma,
    const float* __restrict__ beta, float* __restrict__ scale,
    float* __restrict__ shift)
{
    int c = blockIdx.x, t = threadIdx.x;
    float s = 0.f, ss = 0.f;
    for (int b = 0; b < 8; ++b) {
        const float* p = x + ((size_t)b * 256 + c) * 2048;
        for (int n = t * 4; n < 2048; n += 1024) {
            float4 v = *(const float4*)(p + n);
            s  += v.x + v.y + v.z + v.w;
            ss += v.x*v.x + v.y*v.y + v.z*v.z + v.w*v.w;
        }
    }
    for (int off = 32; off > 0; off >>= 1) {
        s  += __shfl_down(s,  off, 64);
        ss += __shfl_down(ss, off, 64);
    }
    __shared__ float rs[4], rss[4];
    int w = t >> 6;
    if ((t & 63) == 0) { rs[w] = s; rss[w] = ss; }
    __syncthreads();
    if (t == 0) {
        float S  = rs[0] + rs[1] + rs[2] + rs[3];
        float SS = rss[0] + rss[1] + rss[2] + rss[3];
        float mean = S * (1.f / 16384.f);
        float var  = SS * (1.f / 16384.f) - mean * mean;
        float rstd = rsqrtf(var + 1e-5f);
        float sc = rstd * gamma[c];
        scale[c] = sc;
        shift[c] = beta[c] - mean * sc;
    }
}

// ------------------------------------------- normalize + transpose to [b][n][c]
__global__ __launch_bounds__(256) void norm_t_kernel(
    const float* __restrict__ x, const float* __restrict__ scale,
    const float* __restrict__ shift, _Float16* __restrict__ ht)
{
    __shared__ float tile[64][65];
    int t = threadIdx.x;
    int b = blockIdx.z, c0 = blockIdx.y * 64, n0 = blockIdx.x * 64;
    int nl = t & 63, cq = t >> 6;
#pragma unroll
    for (int r = 0; r < 16; ++r) {
        int cl = cq * 16 + r;
        float v = x[((size_t)b * 256 + c0 + cl) * 2048 + n0 + nl];
        tile[cl][nl] = v * scale[c0 + cl] + shift[c0 + cl];
    }
    __syncthreads();
    int cl2 = t & 63, nq = t >> 6;
#pragma unroll
    for (int r = 0; r < 16; ++r) {
        int nl2 = nq * 16 + r;
        ht[((size_t)b * 2048 + n0 + nl2) * 256 + c0 + cl2] = (_Float16)tile[cl2][nl2];
    }
}

// ---------------------------------------------------------------- generic NT GEMM
// C[i][j] = sum_k A[i][k] * B[j][k]  (+ bias, + optional residual), K = 256 fixed.
template<typename OT, bool BIAS_I, bool RES>
__global__ __launch_bounds__(256) void gemm_nt(
    const _Float16* __restrict__ Aall, long strideA,
    const _Float16* __restrict__ Ball, long strideB,
    const float* __restrict__ bias,
    const float* __restrict__ resid, long strideR,
    OT* __restrict__ Call, long strideC,
    int M, int Nn)
{
    constexpr int K = 256;
    int b = blockIdx.z;
    const _Float16* A  = Aall + (size_t)b * strideA;
    const _Float16* Bm = Ball + (size_t)b * strideB;
    OT* C = Call + (size_t)b * strideC;
    int i0 = blockIdx.y * 128, j0 = blockIdx.x * 128;
    __shared__ _Float16 Al[128][40];
    __shared__ _Float16 Bl[128][40];
    int t = threadIdx.x, lane = t & 63, w = t >> 6;
    int lr = lane & 15, lg = lane >> 4;
    int wm = w >> 1, wn = w & 1;
    f32x4 acc[4][4] = {};
    int sr = t >> 1, sh = (t & 1) * 16;
    for (int kk = 0; kk < 8; ++kk) {
        const _Float16* ga = A  + (size_t)(i0 + sr) * K + kk * 32 + sh;
        const _Float16* gb = Bm + (size_t)(j0 + sr) * K + kk * 32 + sh;
        int4 a0 = *(const int4*)ga, a1 = *(const int4*)(ga + 8);
        int4 b0 = *(const int4*)gb, b1 = *(const int4*)(gb + 8);
        *(int4*)&Al[sr][sh] = a0; *(int4*)&Al[sr][sh + 8] = a1;
        *(int4*)&Bl[sr][sh] = b0; *(int4*)&Bl[sr][sh + 8] = b1;
        __syncthreads();
        f16x8 af[4], bf[4];
#pragma unroll
        for (int f = 0; f < 4; ++f) af[f] = *(const f16x8*)&Al[wm * 64 + f * 16 + lr][8 * lg];
#pragma unroll
        for (int f = 0; f < 4; ++f) bf[f] = *(const f16x8*)&Bl[wn * 64 + f * 16 + lr][8 * lg];
#pragma unroll
        for (int fm = 0; fm < 4; ++fm)
#pragma unroll
            for (int fn = 0; fn < 4; ++fn)
                acc[fm][fn] = MFMA16(af[fm], bf[fn], acc[fm][fn]);
        __syncthreads();
    }
#pragma unroll
    for (int fm = 0; fm < 4; ++fm)
#pragma unroll
        for (int fn = 0; fn < 4; ++fn)
#pragma unroll
            for (int rr = 0; rr < 4; ++rr) {
                int row = i0 + wm * 64 + fm * 16 + lg * 4 + rr;
                int col = j0 + wn * 64 + fn * 16 + lr;
                float vv = acc[fm][fn][rr] + (BIAS_I ? bias[row] : bias[col]);
                if (RES) vv += resid[(size_t)b * strideR + (size_t)row * Nn + col];
                C[(size_t)row * Nn + col] = (OT)vv;
            }
}

// ---------------------------------------------------------------- flash attention
// q,k: [b][n][c] f16 ; v: [b][c][n] f16 ; out: [b][n][c] f16
__global__ __launch_bounds__(256) void attn_kernel(
    const _Float16* __restrict__ qb, const _Float16* __restrict__ kb,
    const _Float16* __restrict__ vb, _Float16* __restrict__ ob)
{
    int b = blockIdx.y, q0 = blockIdx.x * 64;
    int t = threadIdx.x, lane = t & 63, w = t >> 6;
    int lr = lane & 15, lg = lane >> 4;
    __shared__ _Float16 Kl[64][264];    // [m][c]
    __shared__ _Float16 Vl[256][72];    // [c][m]
    __shared__ _Float16 Pl[4][16][72];  // per-wave [q][m]

    // Q fragments (wave's 16 q-rows), held in registers for the whole kernel
    f16x8 qf[8];
    {
        const _Float16* qp = qb + ((size_t)b * 2048 + q0 + w * 16 + lr) * 256 + 8 * lg;
#pragma unroll
        for (int g = 0; g < 8; ++g) qf[g] = *(const f16x8*)(qp + g * 32);
    }
    f32x4 oacc[16] = {};
    float m_run[4], l_run[4];
#pragma unroll
    for (int r = 0; r < 4; ++r) { m_run[r] = -1e30f; l_run[r] = 0.f; }

    for (int m0 = 0; m0 < 2048; m0 += 64) {
        // stage K tile: direct row copy  k[b][m0+m][*]
        {
            int mr = t >> 2, part = t & 3;
            const int4* src = (const int4*)(kb + ((size_t)b * 2048 + m0 + mr) * 256 + part * 64);
            int4* dst = (int4*)&Kl[mr][part * 64];
#pragma unroll
            for (int u = 0; u < 8; ++u) dst[u] = src[u];
        }
        // stage V tile: direct row-slice copy  v[b][c][m0..m0+64]
        {
            int part = t & 3;
            for (int cc = t >> 2; cc < 256; cc += 64) {
                const int4* src = (const int4*)(vb + ((size_t)b * 256 + cc) * 2048 + m0 + part * 16);
                int4* dst = (int4*)&Vl[cc][part * 16];
                dst[0] = src[0]; dst[1] = src[1];
            }
        }
        __syncthreads();

        // S = Q K^T  (wave's 16 q-rows x 64 m-cols)
        f32x4 s[4] = {};
#pragma unroll
        for (int kk = 0; kk < 8; ++kk) {
            f16x8 a = qf[kk];
#pragma unroll
            for (int fn = 0; fn < 4; ++fn) {
                f16x8 bb = *(const f16x8*)&Kl[fn * 16 + lr][kk * 32 + 8 * lg];
                s[fn] = MFMA16(a, bb, s[fn]);
            }
        }
        // scale 1/sqrt(256)
#pragma unroll
        for (int f = 0; f < 4; ++f)
#pragma unroll
            for (int r = 0; r < 4; ++r) s[f][r] *= 0.0625f;

        // online softmax: rows live in 16-lane groups (row = lg*4 + r)
        float rowmax[4];
#pragma unroll
        for (int r = 0; r < 4; ++r)
            rowmax[r] = fmaxf(fmaxf(s[0][r], s[1][r]), fmaxf(s[2][r], s[3][r]));
#pragma unroll
        for (int off = 1; off < 16; off <<= 1)
#pragma unroll
            for (int r = 0; r < 4; ++r)
                rowmax[r] = fmaxf(rowmax[r], __shfl_xor(rowmax[r], off, 64));

        float mnew[4], alpha[4], psum[4];
#pragma unroll
        for (int r = 0; r < 4; ++r) {
            mnew[r] = fmaxf(m_run[r], rowmax[r]);
            alpha[r] = __expf(m_run[r] - mnew[r]);
            m_run[r] = mnew[r];
            psum[r] = 0.f;
        }
        _Float16 pbv[4][4];
#pragma unroll
        for (int f = 0; f < 4; ++f)
#pragma unroll
            for (int r = 0; r < 4; ++r) {
                float p = __expf(s[f][r] - mnew[r]);
                _Float16 ph = (_Float16)p;
                pbv[f][r] = ph;
                psum[r] += (float)ph;   // sum what PV actually uses
            }
#pragma unroll
        for (int off = 1; off < 16; off <<= 1)
#pragma unroll
            for (int r = 0; r < 4; ++r)
                psum[r] += __shfl_xor(psum[r], off, 64);
#pragma unroll
        for (int r = 0; r < 4; ++r)
            l_run[r] = l_run[r] * alpha[r] + psum[r];
#pragma unroll
        for (int f = 0; f < 16; ++f)
#pragma unroll
            for (int r = 0; r < 4; ++r)
                oacc[f][r] *= alpha[r];

        // P: C/D layout -> A layout via per-wave LDS buffer
#pragma unroll
        for (int f = 0; f < 4; ++f)
#pragma unroll
            for (int r = 0; r < 4; ++r)
                Pl[w][lg * 4 + r][f * 16 + lr] = pbv[f][r];
        __syncthreads();   // also covers cross-lane P visibility

        // O += P V
#pragma unroll
        for (int ks = 0; ks < 2; ++ks) {
            f16x8 pa = *(const f16x8*)&Pl[w][lr][ks * 32 + 8 * lg];
#pragma unroll
            for (int f = 0; f < 16; ++f) {
                f16x8 vv = *(const f16x8*)&Vl[f * 16 + lr][ks * 32 + 8 * lg];
                oacc[f] = MFMA16(pa, vv, oacc[f]);
            }
        }
        __syncthreads();   // protect Kl/Vl before next stage
    }

    // epilogue: normalize and write [b][n][c]
    float inv[4];
#pragma unroll
    for (int r = 0; r < 4; ++r) inv[r] = 1.0f / l_run[r];
#pragma unroll
    for (int f = 0; f < 16; ++f)
#pragma unroll
        for (int r = 0; r < 4; ++r) {
            int row = q0 + w * 16 + lg * 4 + r;
            int col = f * 16 + lr;
            ob[((size_t)b * 2048 + row) * 256 + col] = (_Float16)(oacc[f][r] * inv[r]);
        }
}

// ---------------------------------------------------------------- launch
extern "C" void kernel_launch(void* const* d_in, const int* in_sizes, int n_in,
                              void* d_out, int out_size, void* d_ws, size_t ws_size,
                              hipStream_t stream) {
    const float* x     = (const float*)d_in[0];
    const float* gamma = (const float*)d_in[1];
    const float* beta  = (const float*)d_in[2];
    const float* Wq    = (const float*)d_in[3];
    const float* bq    = (const float*)d_in[4];
    const float* Wk    = (const float*)d_in[5];
    const float* bk    = (const float*)d_in[6];
    const float* Wv    = (const float*)d_in[7];
    const float* bv    = (const float*)d_in[8];
    const float* Wp    = (const float*)d_in[9];
    const float* bp    = (const float*)d_in[10];
    float* out = (float*)d_out;

    char* ws = (char*)d_ws;
    float* scale = (float*)ws;
    float* shift = scale + 256;
    _Float16* wbf = (_Float16*)(ws + 2048);
    _Float16* Wqh = wbf;
    _Float16* Wkh = wbf + 65536;
    _Float16* Wvh = wbf + 131072;
    _Float16* Wph = wbf + 196608;
    _Float16* ht   = (_Float16*)(ws + 614400);   // 600 KB header
    _Float16* qbuf = ht   + 4194304;
    _Float16* kbuf = qbuf + 4194304;
    _Float16* vbuf = kbuf + 4194304;
    _Float16* abuf = ht;                          // ht dead after v-proj: reuse

    const long SB = 524288;  // per-batch elements (2048*256)

    prep_w_kernel<<<1024, 256, 0, stream>>>(Wq, Wk, Wv, Wp, wbf);
    bn_stats_kernel<<<256, 256, 0, stream>>>(x, gamma, beta, scale, shift);
    norm_t_kernel<<<dim3(32, 4, 8), 256, 0, stream>>>(x, scale, shift, ht);
    // q[b][n][o] = ht[b][n][c] . Wq[o][c] + bq[o]
    gemm_nt<_Float16, false, false><<<dim3(2, 16, 8), 256, 0, stream>>>(
        ht, SB, Wqh, 0, bq, nullptr, 0, qbuf, SB, 2048, 256);
    gemm_nt<_Float16, false, false><<<dim3(2, 16, 8), 256, 0, stream>>>(
        ht, SB, Wkh, 0, bk, nullptr, 0, kbuf, SB, 2048, 256);
    // v[b][o][n] = Wv[o][c] . ht[b][n][c] + bv[o]
    gemm_nt<_Float16, true, false><<<dim3(16, 2, 8), 256, 0, stream>>>(
        Wvh, 0, ht, SB, bv, nullptr, 0, vbuf, SB, 256, 2048);
    attn_kernel<<<dim3(32, 8), 256, 0, stream>>>(qbuf, kbuf, vbuf, abuf);
    // out[b][o][n] = Wp[o][c] . attn[b][n][c] + bp[o] + x[b][o][n]
    gemm_nt<float, true, true><<<dim3(16, 2, 8), 256, 0, stream>>>(
        Wph, 0, abuf, SB, bp, x, SB, out, SB, 256, 2048);
}

// Round 2
// 146.894 us; speedup vs baseline: 1.4454x; 1.4454x over previous
//
#include <hip/hip_runtime.h>
#include <hip/hip_fp16.h>

typedef _Float16 __attribute__((ext_vector_type(8))) f16x8;
typedef float __attribute__((ext_vector_type(4))) f32x4;

#define MFMA16(a, b, c) __builtin_amdgcn_mfma_f32_16x16x32_f16(a, b, c, 0, 0, 0)

__device__ __forceinline__ void gload_lds16(const _Float16* g, void* l) {
    __builtin_amdgcn_global_load_lds(
        (const __attribute__((address_space(1))) void*)g,
        (__attribute__((address_space(3))) void*)l, 16, 0, 0);
}

// ---------------------------------------------------------------- prep weights
__global__ __launch_bounds__(256) void prep_w_kernel(
    const float* __restrict__ Wq, const float* __restrict__ Wk,
    const float* __restrict__ Wv, const float* __restrict__ Wp,
    const float* __restrict__ bq, const float* __restrict__ bk,
    _Float16* __restrict__ out, float* __restrict__ bqk)
{
    int bid = blockIdx.x;
    int t = threadIdx.x;
    if (bid == 1024) {                       // bias concat block
        bqk[t]       = bq[t];
        bqk[256 + t] = bk[t];
        return;
    }
    int i = bid * 256 + t;                   // 262144 total
    int w = i >> 16, j = i & 65535;
    const float* src = (w == 0) ? Wq : (w == 1) ? Wk : (w == 2) ? Wv : Wp;
    out[i] = (_Float16)src[j];
}

// ---------------------------------------------------------------- BN stats
__global__ __launch_bounds__(256) void bn_stats_kernel(
    const float* __restrict__ x, const float* __restrict__ gamma,
    const float* __restrict__ beta, float* __restrict__ scale,
    float* __restrict__ shift)
{
    int c = blockIdx.x, t = threadIdx.x;
    float s = 0.f, ss = 0.f;
    for (int b = 0; b < 8; ++b) {
        const float* p = x + ((size_t)b * 256 + c) * 2048;
        for (int n = t * 4; n < 2048; n += 1024) {
            float4 v = *(const float4*)(p + n);
            s  += v.x + v.y + v.z + v.w;
            ss += v.x*v.x + v.y*v.y + v.z*v.z + v.w*v.w;
        }
    }
    for (int off = 32; off > 0; off >>= 1) {
        s  += __shfl_down(s,  off, 64);
        ss += __shfl_down(ss, off, 64);
    }
    __shared__ float rs[4], rss[4];
    int w = t >> 6;
    if ((t & 63) == 0) { rs[w] = s; rss[w] = ss; }
    __syncthreads();
    if (t == 0) {
        float S  = rs[0] + rs[1] + rs[2] + rs[3];
        float SS = rss[0] + rss[1] + rss[2] + rss[3];
        float mean = S * (1.f / 16384.f);
        float var  = SS * (1.f / 16384.f) - mean * mean;
        float rstd = rsqrtf(var + 1e-5f);
        float sc = rstd * gamma[c];
        scale[c] = sc;
        shift[c] = beta[c] - mean * sc;
    }
}

// ------------------------------------------- normalize + transpose to [b][n][c]
__global__ __launch_bounds__(256) void norm_t_kernel(
    const float* __restrict__ x, const float* __restrict__ scale,
    const float* __restrict__ shift, _Float16* __restrict__ ht)
{
    __shared__ float tile[64][65];
    int t = threadIdx.x;
    int b = blockIdx.z, c0 = blockIdx.y * 64, n0 = blockIdx.x * 64;
    int nl = t & 63, cq = t >> 6;
#pragma unroll
    for (int r = 0; r < 16; ++r) {
        int cl = cq * 16 + r;
        float v = x[((size_t)b * 256 + c0 + cl) * 2048 + n0 + nl];
        tile[cl][nl] = v * scale[c0 + cl] + shift[c0 + cl];
    }
    __syncthreads();
    int cl2 = t & 63, nq = t >> 6;
#pragma unroll
    for (int r = 0; r < 16; ++r) {
        int nl2 = nq * 16 + r;
        ht[((size_t)b * 2048 + n0 + nl2) * 256 + c0 + cl2] = (_Float16)tile[cl2][nl2];
    }
}

// ---------------------------------------------------------------- generic NT GEMM
// C[i][j] = sum_k A[i][k] * B[j][k]  (+ bias, + optional residual), K = 256 fixed.
template<typename OT, bool BIAS_I, bool RES>
__global__ __launch_bounds__(256) void gemm_nt(
    const _Float16* __restrict__ Aall, long strideA,
    const _Float16* __restrict__ Ball, long strideB,
    const float* __restrict__ bias,
    const float* __restrict__ resid, long strideR,
    OT* __restrict__ Call, long strideC,
    int M, int Nn)
{
    constexpr int K = 256;
    int b = blockIdx.z;
    const _Float16* A  = Aall + (size_t)b * strideA;
    const _Float16* Bm = Ball + (size_t)b * strideB;
    OT* C = Call + (size_t)b * strideC;
    int i0 = blockIdx.y * 128, j0 = blockIdx.x * 128;
    __shared__ _Float16 Al[128][40];
    __shared__ _Float16 Bl[128][40];
    int t = threadIdx.x, lane = t & 63, w = t >> 6;
    int lr = lane & 15, lg = lane >> 4;
    int wm = w >> 1, wn = w & 1;
    f32x4 acc[4][4] = {};
    int sr = t >> 1, sh = (t & 1) * 16;
    for (int kk = 0; kk < 8; ++kk) {
        const _Float16* ga = A  + (size_t)(i0 + sr) * K + kk * 32 + sh;
        const _Float16* gb = Bm + (size_t)(j0 + sr) * K + kk * 32 + sh;
        int4 a0 = *(const int4*)ga, a1 = *(const int4*)(ga + 8);
        int4 b0 = *(const int4*)gb, b1 = *(const int4*)(gb + 8);
        *(int4*)&Al[sr][sh] = a0; *(int4*)&Al[sr][sh + 8] = a1;
        *(int4*)&Bl[sr][sh] = b0; *(int4*)&Bl[sr][sh + 8] = b1;
        __syncthreads();
        f16x8 af[4], bf[4];
#pragma unroll
        for (int f = 0; f < 4; ++f) af[f] = *(const f16x8*)&Al[wm * 64 + f * 16 + lr][8 * lg];
#pragma unroll
        for (int f = 0; f < 4; ++f) bf[f] = *(const f16x8*)&Bl[wn * 64 + f * 16 + lr][8 * lg];
#pragma unroll
        for (int fm = 0; fm < 4; ++fm)
#pragma unroll
            for (int fn = 0; fn < 4; ++fn)
                acc[fm][fn] = MFMA16(af[fm], bf[fn], acc[fm][fn]);
        __syncthreads();
    }
#pragma unroll
    for (int fm = 0; fm < 4; ++fm)
#pragma unroll
        for (int fn = 0; fn < 4; ++fn)
#pragma unroll
            for (int rr = 0; rr < 4; ++rr) {
                int row = i0 + wm * 64 + fm * 16 + lg * 4 + rr;
                int col = j0 + wn * 64 + fn * 16 + lr;
                float vv = acc[fm][fn][rr] + (BIAS_I ? bias[row] : bias[col]);
                if (RES) vv += resid[(size_t)b * strideR + (size_t)row * Nn + col];
                C[(size_t)row * Nn + col] = (OT)vv;
            }
}

// ---------------------------------------------------------------- flash attention
// qk: [b][n][512] f16 (q cols 0..255, k cols 256..511); v: [b][c][n] f16
// KV split in 2: partial unnormalized O (f16) + m,l (f32) per split.
__global__ __launch_bounds__(256, 2) void attn_kernel(
    const _Float16* __restrict__ qk, const _Float16* __restrict__ vb,
    _Float16* __restrict__ Opart, float* __restrict__ mpart,
    float* __restrict__ lpart)
{
    int id = blockIdx.x;
    int b = id & 7;                 // batch -> XCD affinity (id%8 ~ XCD)
    int k2 = id >> 3;
    int qb = k2 & 31, sp = k2 >> 5;
    int q0 = qb * 64;
    int m_base = sp * 1024;

    __shared__ __align__(16) char Kraw[2 * 16384];   // [m<32][512B] XOR-swizzled
    __shared__ __align__(16) char Vraw[2 * 16384];   // [c<256] octet-rotated
    __shared__ _Float16 Pl[4][16][40];

    int t = threadIdx.x, lane = t & 63, w = t >> 6;
    int lr = lane & 15, lg = lane >> 4;

    const _Float16* kgbase = qk + (size_t)b * 1048576 + 256;
    const _Float16* vgbase = vb + (size_t)b * 524288;

    // per-lane staging source offsets (elements), constant across tiles
    int kofs[4], vofs[4];
#pragma unroll
    for (int u = 0; u < 4; ++u) {
        int iu = w * 4 + u;
        int m_loc = iu * 2 + (lane >> 5);
        int offB = ((lane & 31) * 16) ^ ((m_loc & 7) << 4);
        kofs[u] = m_loc * 512 + (offB >> 1);
        int S = iu * 64 + lane;
        int g2 = S >> 3, w8 = S & 7;
        int c = 2 * g2 + (w8 >> 2);
        int o = ((w8 & 3) - (g2 & 3)) & 3;
        vofs[u] = c * 2048 + o * 8;
    }

    // Q fragments: wave's 16 q-rows, in registers for the whole kernel
    f16x8 qf[8];
    {
        const _Float16* qp = qk + ((size_t)b * 2048 + q0 + w * 16 + lr) * 512 + 8 * lg;
#pragma unroll
        for (int g = 0; g < 8; ++g) qf[g] = *(const f16x8*)(qp + g * 32);
    }

    f32x4 oacc[16] = {};
    float m_run[4], l_run[4];
#pragma unroll
    for (int r = 0; r < 4; ++r) { m_run[r] = -1e30f; l_run[r] = 0.f; }

    int swzK = (lr & 7) << 4;      // K read swizzle, lane-constant
    // V read offset within a 1KB f-chunk, lane-constant
    int voffc = (lr >> 1) * 128 + ((lr & 1) * 4 + ((lg + (lr >> 1)) & 3)) * 16;

    // prologue: stage tile 0 into buffer 0
    {
        char* kd = Kraw + w * 4096;
        char* vd = Vraw + w * 4096;
#pragma unroll
        for (int u = 0; u < 4; ++u) {
            gload_lds16(kgbase + (size_t)m_base * 512 + kofs[u], kd + u * 1024);
            gload_lds16(vgbase + m_base + vofs[u], vd + u * 1024);
        }
    }
    __syncthreads();

    int cur = 0;
    for (int tt = 0; tt < 32; ++tt) {
        // issue next tile's staging into the other buffer (overlaps compute)
        if (tt + 1 < 32) {
            int n0 = m_base + (tt + 1) * 32;
            char* kd = Kraw + (cur ^ 1) * 16384 + w * 4096;
            char* vd = Vraw + (cur ^ 1) * 16384 + w * 4096;
#pragma unroll
            for (int u = 0; u < 4; ++u) {
                gload_lds16(kgbase + (size_t)n0 * 512 + kofs[u], kd + u * 1024);
                gload_lds16(vgbase + n0 + vofs[u], vd + u * 1024);
            }
        }
        const char* kbase = Kraw + cur * 16384;
        const char* vbase2 = Vraw + cur * 16384;

        // S = Q K^T  (16 q-rows x 32 m-cols)
        f32x4 s[2] = {};
        __builtin_amdgcn_s_setprio(1);
#pragma unroll
        for (int kk = 0; kk < 8; ++kk) {
            f16x8 a = qf[kk];
#pragma unroll
            for (int fn = 0; fn < 2; ++fn) {
                f16x8 bb = *(const f16x8*)(kbase + (fn * 16 + lr) * 512 +
                                           ((kk * 64 + lg * 16) ^ swzK));
                s[fn] = MFMA16(a, bb, s[fn]);
            }
        }
        __builtin_amdgcn_s_setprio(0);

#pragma unroll
        for (int f = 0; f < 2; ++f)
#pragma unroll
            for (int r = 0; r < 4; ++r) s[f][r] *= 0.0625f;

        // online softmax over 16-lane row groups
        float rowmax[4];
#pragma unroll
        for (int r = 0; r < 4; ++r) rowmax[r] = fmaxf(s[0][r], s[1][r]);
#pragma unroll
        for (int off = 1; off < 16; off <<= 1)
#pragma unroll
            for (int r = 0; r < 4; ++r)
                rowmax[r] = fmaxf(rowmax[r], __shfl_xor(rowmax[r], off, 64));

        float mnew[4], alpha[4], psum[4];
#pragma unroll
        for (int r = 0; r < 4; ++r) {
            mnew[r] = fmaxf(m_run[r], rowmax[r]);
            alpha[r] = __expf(m_run[r] - mnew[r]);
            m_run[r] = mnew[r];
            psum[r] = 0.f;
        }
        _Float16 pbv[2][4];
#pragma unroll
        for (int f = 0; f < 2; ++f)
#pragma unroll
            for (int r = 0; r < 4; ++r) {
                float p = __expf(s[f][r] - mnew[r]);
                _Float16 ph = (_Float16)p;
                pbv[f][r] = ph;
                psum[r] += (float)ph;
            }
#pragma unroll
        for (int off = 1; off < 16; off <<= 1)
#pragma unroll
            for (int r = 0; r < 4; ++r)
                psum[r] += __shfl_xor(psum[r], off, 64);
#pragma unroll
        for (int r = 0; r < 4; ++r)
            l_run[r] = l_run[r] * alpha[r] + psum[r];
#pragma unroll
        for (int f = 0; f < 16; ++f)
#pragma unroll
            for (int r = 0; r < 4; ++r)
                oacc[f][r] *= alpha[r];

        // P: C/D layout -> A layout via wave-private LDS (no barrier needed)
#pragma unroll
        for (int f = 0; f < 2; ++f)
#pragma unroll
            for (int r = 0; r < 4; ++r)
                Pl[w][lg * 4 + r][f * 16 + lr] = pbv[f][r];

        // O += P V
        f16x8 pa = *(const f16x8*)&Pl[w][lr][8 * lg];
        __builtin_amdgcn_s_setprio(1);
#pragma unroll
        for (int f = 0; f < 16; ++f) {
            f16x8 vv = *(const f16x8*)(vbase2 + f * 1024 + voffc);
            oacc[f] = MFMA16(pa, vv, oacc[f]);
        }
        __builtin_amdgcn_s_setprio(0);

        __syncthreads();   // drains this wave's staging loads; flips buffers safely
        cur ^= 1;
    }

    // epilogue: write unnormalized partial O + (m, l)
    _Float16* od = Opart + (size_t)sp * 4194304 + (size_t)b * 2048 * 256;
#pragma unroll
    for (int f = 0; f < 16; ++f)
#pragma unroll
        for (int r = 0; r < 4; ++r) {
            int row = q0 + w * 16 + lg * 4 + r;
            od[(size_t)row * 256 + f * 16 + lr] = (_Float16)oacc[f][r];
        }
    if (lr == 0) {
        float* mp = mpart + sp * 16384 + b * 2048;
        float* lp = lpart + sp * 16384 + b * 2048;
#pragma unroll
        for (int r = 0; r < 4; ++r) {
            int row = q0 + w * 16 + lg * 4 + r;
            mp[row] = m_run[r];
            lp[row] = l_run[r];
        }
    }
}

// ---------------------------------------------------------------- split combine
__global__ __launch_bounds__(256) void combine_kernel(
    const _Float16* __restrict__ Opart, const float* __restrict__ mpart,
    const float* __restrict__ lpart, _Float16* __restrict__ abuf)
{
    int idx = blockIdx.x * 256 + threadIdx.x;   // 524288 chunks of 8
    int rg = idx >> 5;
    int c8 = (idx & 31) << 3;
    float m0 = mpart[rg], m1 = mpart[16384 + rg];
    float l0 = lpart[rg], l1 = lpart[16384 + rg];
    float mx = fmaxf(m0, m1);
    float w0 = __expf(m0 - mx), w1 = __expf(m1 - mx);
    float inv = 1.f / (w0 * l0 + w1 * l1);
    f16x8 a = *(const f16x8*)(Opart + (size_t)rg * 256 + c8);
    f16x8 bb = *(const f16x8*)(Opart + 4194304 + (size_t)rg * 256 + c8);
    f16x8 r;
#pragma unroll
    for (int j = 0; j < 8; ++j)
        r[j] = (_Float16)(((float)a[j] * w0 + (float)bb[j] * w1) * inv);
    *(f16x8*)(abuf + (size_t)rg * 256 + c8) = r;
}

// ---------------------------------------------------------------- launch
extern "C" void kernel_launch(void* const* d_in, const int* in_sizes, int n_in,
                              void* d_out, int out_size, void* d_ws, size_t ws_size,
                              hipStream_t stream) {
    const float* x     = (const float*)d_in[0];
    const float* gamma = (const float*)d_in[1];
    const float* beta  = (const float*)d_in[2];
    const float* Wq    = (const float*)d_in[3];
    const float* bq    = (const float*)d_in[4];
    const float* Wk    = (const float*)d_in[5];
    const float* bk    = (const float*)d_in[6];
    const float* Wv    = (const float*)d_in[7];
    const float* bv    = (const float*)d_in[8];
    const float* Wp    = (const float*)d_in[9];
    const float* bp    = (const float*)d_in[10];
    float* out = (float*)d_out;

    char* ws = (char*)d_ws;
    float* scale = (float*)ws;                         // 256 f32
    float* shift = (float*)(ws + 1024);                // 256 f32
    float* bqk   = (float*)(ws + 2048);                // 512 f32
    _Float16* wbf  = (_Float16*)(ws + 8192);           // 4x65536 f16
    _Float16* Wvh  = wbf + 131072;
    _Float16* Wph  = wbf + 196608;
    _Float16* ht   = (_Float16*)(ws + 1048576);        // [8][2048][256]
    _Float16* qkbuf = (_Float16*)(ws + 9437184);       // [8][2048][512]
    _Float16* vbuf  = (_Float16*)(ws + 26214400);      // [8][256][2048]
    _Float16* Opart = (_Float16*)(ws + 34603008);      // [2][8][2048][256]
    float* mpart = (float*)(ws + 51380224);            // [2][16384]
    float* lpart = (float*)(ws + 51511296);            // [2][16384]
    _Float16* abuf = ht;                               // ht dead after v-proj

    const long SB = 524288;   // per-batch elements (2048*256)

    prep_w_kernel<<<1025, 256, 0, stream>>>(Wq, Wk, Wv, Wp, bq, bk, wbf, bqk);
    bn_stats_kernel<<<256, 256, 0, stream>>>(x, gamma, beta, scale, shift);
    norm_t_kernel<<<dim3(32, 4, 8), 256, 0, stream>>>(x, scale, shift, ht);
    // [q|k][b][n][512] = ht[b][n][c] . [Wq;Wk][o][c] + bqk
    gemm_nt<_Float16, false, false><<<dim3(4, 16, 8), 256, 0, stream>>>(
        ht, SB, wbf, 0, bqk, nullptr, 0, qkbuf, 1048576, 2048, 512);
    // v[b][o][n] = Wv[o][c] . ht[b][n][c] + bv[o]
    gemm_nt<_Float16, true, false><<<dim3(16, 2, 8), 256, 0, stream>>>(
        Wvh, 0, ht, SB, bv, nullptr, 0, vbuf, SB, 256, 2048);
    attn_kernel<<<512, 256, 0, stream>>>(qkbuf, vbuf, Opart, mpart, lpart);
    combine_kernel<<<2048, 256, 0, stream>>>(Opart, mpart, lpart, abuf);
    // out[b][o][n] = Wp[o][c] . attn[b][n][c] + bp[o] + x[b][o][n]
    gemm_nt<float, true, true><<<dim3(16, 2, 8), 256, 0, stream>>>(
        Wph, 0, abuf, SB, bp, x, SB, out, SB, 256, 2048);
}

// Round 4
// 127.521 us; speedup vs baseline: 1.6650x; 1.1519x over previous
//
#include <hip/hip_runtime.h>
#include <hip/hip_fp16.h>

typedef _Float16 f16x8 __attribute__((ext_vector_type(8)));
typedef _Float16 f16x4 __attribute__((ext_vector_type(4)));
typedef float f32x4 __attribute__((ext_vector_type(4)));
typedef float f32x16 __attribute__((ext_vector_type(16)));

#define MFMA16(a, b, c) __builtin_amdgcn_mfma_f32_16x16x32_f16(a, b, c, 0, 0, 0)
#define MFMA32(a, b, c) __builtin_amdgcn_mfma_f32_32x32x16_f16(a, b, c, 0, 0, 0)

__device__ __forceinline__ void gload_lds16(const _Float16* g, void* l) {
    __builtin_amdgcn_global_load_lds(
        (const __attribute__((address_space(1))) void*)g,
        (__attribute__((address_space(3))) void*)l, 16, 0, 0);
}

__device__ __forceinline__ unsigned pkh(float a, float b) {
    typedef __fp16 fp16v2 __attribute__((ext_vector_type(2)));
    fp16v2 h = __builtin_amdgcn_cvt_pkrtz(a, b);
    return __builtin_bit_cast(unsigned, h);
}

// ---------------------------------------------------------------- prep weights
__global__ __launch_bounds__(256) void prep_w_kernel(
    const float* __restrict__ Wq, const float* __restrict__ Wk,
    const float* __restrict__ Wv, const float* __restrict__ Wp,
    const float* __restrict__ bq, const float* __restrict__ bk,
    _Float16* __restrict__ out, float* __restrict__ bqk)
{
    int bid = blockIdx.x;
    int t = threadIdx.x;
    if (bid == 1024) {
        bqk[t]       = bq[t];
        bqk[256 + t] = bk[t];
        return;
    }
    int i = bid * 256 + t;
    int w = i >> 16, j = i & 65535;
    const float* src = (w == 0) ? Wq : (w == 1) ? Wk : (w == 2) ? Wv : Wp;
    out[i] = (_Float16)src[j];
}

// ---------------------------------------------------------------- BN stats
__global__ __launch_bounds__(256) void bn_stats_kernel(
    const float* __restrict__ x, const float* __restrict__ gamma,
    const float* __restrict__ beta, float* __restrict__ scale,
    float* __restrict__ shift)
{
    int c = blockIdx.x, t = threadIdx.x;
    float s = 0.f, ss = 0.f;
    for (int b = 0; b < 8; ++b) {
        const float* p = x + ((size_t)b * 256 + c) * 2048;
        for (int n = t * 4; n < 2048; n += 1024) {
            float4 v = *(const float4*)(p + n);
            s  += v.x + v.y + v.z + v.w;
            ss += v.x*v.x + v.y*v.y + v.z*v.z + v.w*v.w;
        }
    }
    for (int off = 32; off > 0; off >>= 1) {
        s  += __shfl_down(s,  off, 64);
        ss += __shfl_down(ss, off, 64);
    }
    __shared__ float rs[4], rss[4];
    int w = t >> 6;
    if ((t & 63) == 0) { rs[w] = s; rss[w] = ss; }
    __syncthreads();
    if (t == 0) {
        float S  = rs[0] + rs[1] + rs[2] + rs[3];
        float SS = rss[0] + rss[1] + rss[2] + rss[3];
        float mean = S * (1.f / 16384.f);
        float var  = SS * (1.f / 16384.f) - mean * mean;
        float rstd = rsqrtf(var + 1e-5f);
        float sc = rstd * gamma[c];
        scale[c] = sc;
        shift[c] = beta[c] - mean * sc;
    }
}

// ------------------------------------------- normalize + transpose to [b][n][c]
__global__ __launch_bounds__(256) void norm_t_kernel(
    const float* __restrict__ x, const float* __restrict__ scale,
    const float* __restrict__ shift, _Float16* __restrict__ ht)
{
    __shared__ float tile[64][65];
    int t = threadIdx.x;
    int b = blockIdx.z, c0 = blockIdx.y * 64, n0 = blockIdx.x * 64;
    int nl = t & 63, cq = t >> 6;
#pragma unroll
    for (int r = 0; r < 16; ++r) {
        int cl = cq * 16 + r;
        float v = x[((size_t)b * 256 + c0 + cl) * 2048 + n0 + nl];
        tile[cl][nl] = v * scale[c0 + cl] + shift[c0 + cl];
    }
    __syncthreads();
    int cl2 = t & 63, nq = t >> 6;
#pragma unroll
    for (int r = 0; r < 16; ++r) {
        int nl2 = nq * 16 + r;
        ht[((size_t)b * 2048 + n0 + nl2) * 256 + c0 + cl2] = (_Float16)tile[cl2][nl2];
    }
}

// ---------------------------------------------------------------- generic NT GEMM
template<typename OT, bool BIAS_I, bool RES>
__global__ __launch_bounds__(256) void gemm_nt(
    const _Float16* __restrict__ Aall, long strideA,
    const _Float16* __restrict__ Ball, long strideB,
    const float* __restrict__ bias,
    const float* __restrict__ resid, long strideR,
    OT* __restrict__ Call, long strideC,
    int M, int Nn)
{
    constexpr int K = 256;
    int b = blockIdx.z;
    const _Float16* A  = Aall + (size_t)b * strideA;
    const _Float16* Bm = Ball + (size_t)b * strideB;
    OT* C = Call + (size_t)b * strideC;
    int i0 = blockIdx.y * 128, j0 = blockIdx.x * 128;
    __shared__ _Float16 Al[128][40];
    __shared__ _Float16 Bl[128][40];
    int t = threadIdx.x, lane = t & 63, w = t >> 6;
    int lr = lane & 15, lg = lane >> 4;
    int wm = w >> 1, wn = w & 1;
    f32x4 acc[4][4] = {};
    int sr = t >> 1, sh = (t & 1) * 16;
    for (int kk = 0; kk < 8; ++kk) {
        const _Float16* ga = A  + (size_t)(i0 + sr) * K + kk * 32 + sh;
        const _Float16* gb = Bm + (size_t)(j0 + sr) * K + kk * 32 + sh;
        int4 a0 = *(const int4*)ga, a1 = *(const int4*)(ga + 8);
        int4 b0 = *(const int4*)gb, b1 = *(const int4*)(gb + 8);
        *(int4*)&Al[sr][sh] = a0; *(int4*)&Al[sr][sh + 8] = a1;
        *(int4*)&Bl[sr][sh] = b0; *(int4*)&Bl[sr][sh + 8] = b1;
        __syncthreads();
        f16x8 af[4], bf[4];
#pragma unroll
        for (int f = 0; f < 4; ++f) af[f] = *(const f16x8*)&Al[wm * 64 + f * 16 + lr][8 * lg];
#pragma unroll
        for (int f = 0; f < 4; ++f) bf[f] = *(const f16x8*)&Bl[wn * 64 + f * 16 + lr][8 * lg];
#pragma unroll
        for (int fm = 0; fm < 4; ++fm)
#pragma unroll
            for (int fn = 0; fn < 4; ++fn)
                acc[fm][fn] = MFMA16(af[fm], bf[fn], acc[fm][fn]);
        __syncthreads();
    }
#pragma unroll
    for (int fm = 0; fm < 4; ++fm)
#pragma unroll
        for (int fn = 0; fn < 4; ++fn)
#pragma unroll
            for (int rr = 0; rr < 4; ++rr) {
                int row = i0 + wm * 64 + fm * 16 + lg * 4 + rr;
                int col = j0 + wn * 64 + fn * 16 + lr;
                float vv = acc[fm][fn][rr] + (BIAS_I ? bias[row] : bias[col]);
                if (RES) vv += resid[(size_t)b * strideR + (size_t)row * Nn + col];
                C[(size_t)row * Nn + col] = (OT)vv;
            }
}

// ---------------------------------------------------------------- flash attention
// 32x32 swapped-QK structure. qk: [b][n][512] f16 (q: cols 0..255 pre-scaled use,
// k: 256..511); v: [b][c][n] f16. Wave owns 32 q-rows; KVBLK=32; dbuf LDS.
// Partials: normalized O (f16, [sp][b][qb][128q][256d]) + m,l f32.
__global__ __launch_bounds__(256, 2) void attn2_kernel(
    const _Float16* __restrict__ qk, const _Float16* __restrict__ vb,
    _Float16* __restrict__ Opart, float* __restrict__ mpart,
    float* __restrict__ lpart, int nsp, int mspan)
{
    int id = blockIdx.x;
    int b = id & 7;                       // batch -> XCD affinity
    int rest = id >> 3;
    int qblk = rest & 15, sp = rest >> 4;
    int m_base = sp * mspan;
    int T = mspan >> 5;                   // tiles of 32 m

    __shared__ __align__(16) char lds[66560];   // loop: 2x(16K K + 16K V); epi: 4x16640 transpose

    int t = threadIdx.x, ln = t & 63, w = t >> 6;
    int col = ln & 31, hi = ln >> 5;

    const _Float16* kg = qk + (size_t)b * 1048576 + 256;
    const _Float16* vg = vb + (size_t)b * 524288;

    // staging source offsets (wave w handles loads n = w*4+i)
    int koffs[4], voffs[4];
#pragma unroll
    for (int i = 0; i < 4; ++i) {
        int n = w * 4 + i;
        koffs[i] = (ln >> 1) * 512 + (ln & 1) * 8 + n * 16;
        voffs[i] = (((n & 7) * 32 + (ln >> 1)) * 2048) + ((n >> 3) * 16) + (ln & 1) * 8;
    }
    int frd = col * 32 + hi * 16;   // fragment read byte offset (K and V alike)

    // Q fragments (B-operand): lane holds Q[q0+col][ks*16 + hi*8 + e], scaled by 1/16
    f16x8 qf[16];
    {
        const _Float16* qp = qk + ((size_t)b * 2048 + qblk * 128 + w * 32 + col) * 512 + hi * 8;
#pragma unroll
        for (int ks = 0; ks < 16; ++ks) {
            f16x8 v = *(const f16x8*)(qp + ks * 16);
#pragma unroll
            for (int e = 0; e < 8; ++e) v[e] = v[e] * (_Float16)0.0625f;
            qf[ks] = v;
        }
    }

    f32x16 oacc[8] = {};
    float m_run = -1e30f, l_run = 0.f;

    // prologue: stage tile 0 into buffer 0
#pragma unroll
    for (int i = 0; i < 4; ++i) {
        int n = w * 4 + i;
        gload_lds16(kg + (size_t)m_base * 512 + koffs[i], lds + n * 1024);
        gload_lds16(vg + m_base + voffs[i], lds + 16384 + n * 1024);
    }
    __syncthreads();

    int buf = 0;
    for (int tt = 0; tt < T; ++tt) {
        if (tt + 1 < T) {
            int m0 = m_base + (tt + 1) * 32;
            char* kb = lds + (buf ^ 1) * 32768;
#pragma unroll
            for (int i = 0; i < 4; ++i) {
                int n = w * 4 + i;
                gload_lds16(kg + (size_t)m0 * 512 + koffs[i], kb + n * 1024);
                gload_lds16(vg + m0 + voffs[i], kb + 16384 + n * 1024);
            }
        }
        const char* kbase = lds + buf * 32768;
        const char* vbase = kbase + 16384;

        // S^T = K Q : C[m][q], col=q lane-local, 16 m-values per lane
        f32x16 sacc = {};
        __builtin_amdgcn_s_setprio(1);
#pragma unroll
        for (int ks = 0; ks < 16; ++ks) {
            f16x8 kf = *(const f16x8*)(kbase + ks * 1024 + frd);
            sacc = MFMA32(kf, qf[ks], sacc);
        }
        __builtin_amdgcn_s_setprio(0);

        // in-register online softmax (row = this lane's q; partner lane ln^32 same q)
        float rm = sacc[0];
#pragma unroll
        for (int i = 1; i < 16; ++i) rm = fmaxf(rm, sacc[i]);
        rm = fmaxf(rm, __shfl_xor(rm, 32, 64));

        if (__any(rm > m_run + 8.0f)) {          // defer-max (T13)
            float mnew = fmaxf(m_run, rm);
            float alpha = __expf(m_run - mnew);
            l_run *= alpha;
#pragma unroll
            for (int dt = 0; dt < 8; ++dt) oacc[dt] *= alpha;
            m_run = mnew;
        }

        float pv_[16], psum = 0.f;
#pragma unroll
        for (int i = 0; i < 16; ++i) { pv_[i] = __expf(sacc[i] - m_run); psum += pv_[i]; }
        psum += __shfl_xor(psum, 32, 64);
        l_run += psum;

        // pack P to f16 quads: W[a][i] = pk(p[4a+2i], p[4a+2i+1]), a = reg>>2
        unsigned W0[2], W1[2], W2[2], W3[2];
        W0[0] = pkh(pv_[0],  pv_[1]);  W0[1] = pkh(pv_[2],  pv_[3]);
        W1[0] = pkh(pv_[4],  pv_[5]);  W1[1] = pkh(pv_[6],  pv_[7]);
        W2[0] = pkh(pv_[8],  pv_[9]);  W2[1] = pkh(pv_[10], pv_[11]);
        W3[0] = pkh(pv_[12], pv_[13]); W3[1] = pkh(pv_[14], pv_[15]);

        // PV: O^T += V^T P^T ; per kstep j exchange partner quad via shfl_xor(32)
        __builtin_amdgcn_s_setprio(1);
#pragma unroll
        for (int j = 0; j < 2; ++j) {
            unsigned A0 = j ? W2[0] : W0[0], A1 = j ? W2[1] : W0[1];
            unsigned B0 = j ? W3[0] : W1[0], B1 = j ? W3[1] : W1[1];
            unsigned s0 = hi ? A0 : B0, s1 = hi ? A1 : B1;
            unsigned r0 = __shfl_xor(s0, 32, 64), r1 = __shfl_xor(s1, 32, 64);
            union { unsigned u[4]; f16x8 v; } pf;
            pf.u[0] = hi ? r0 : A0; pf.u[1] = hi ? r1 : A1;
            pf.u[2] = hi ? B0 : r0; pf.u[3] = hi ? B1 : r1;
#pragma unroll
            for (int dt = 0; dt < 8; ++dt) {
                f16x8 vf = *(const f16x8*)(vbase + j * 8192 + dt * 1024 + frd);
                oacc[dt] = MFMA32(vf, pf.v, oacc[dt]);
            }
        }
        __builtin_amdgcn_s_setprio(0);

        __syncthreads();
        buf ^= 1;
    }

    // epilogue: normalize, transpose via wave-private LDS, coalesced write
    __syncthreads();                       // all waves done with K/V buffers
    _Float16* tr = (_Float16*)(lds + w * 16640);   // [32 q][260 d-stride]
    float invl = 1.0f / l_run;
#pragma unroll
    for (int dt = 0; dt < 8; ++dt)
#pragma unroll
        for (int g = 0; g < 4; ++g) {
            f16x4 q4;
#pragma unroll
            for (int e = 0; e < 4; ++e) q4[e] = (_Float16)(oacc[dt][g * 4 + e] * invl);
            int d0 = dt * 32 + g * 8 + 4 * hi;
            *(f16x4*)(tr + col * 260 + d0) = q4;
        }
    // per-wave region, same-wave read-back: lgkmcnt ordering suffices
    size_t region = ((size_t)((sp * 8 + b) * 16 + qblk)) * 32768;
    int rrow = ln >> 1, h = ln & 1;
    const _Float16* srcr = tr + rrow * 260 + h * 128;
    _Float16* dstr = Opart + region + (size_t)(w * 32 + rrow) * 256 + h * 128;
#pragma unroll
    for (int i = 0; i < 16; ++i)
        *(f16x8*)(dstr + i * 8) = *(const f16x8*)(srcr + i * 8);

    if (hi == 0) {
        int qi = w * 32 + col;
        int base = ((sp * 8 + b) * 16 + qblk) * 128 + qi;
        mpart[base] = m_run;
        lpart[base] = l_run;
    }
}

// ---------------------------------------------------------------- split combine
__global__ __launch_bounds__(256) void combine2_kernel(
    const _Float16* __restrict__ Opart, const float* __restrict__ mpart,
    const float* __restrict__ lpart, _Float16* __restrict__ abuf, int nsp)
{
    int id = blockIdx.x;
    int b = id & 7, qb = (id >> 3) & 15, dh = id >> 7;
    int t = threadIdx.x;
    __shared__ float cf[4][128];
    if (t < 128) {
        float m[4], l[4], mx = -1e30f;
        for (int sp = 0; sp < nsp; ++sp) {
            int base = ((sp * 8 + b) * 16 + qb) * 128 + t;
            m[sp] = mpart[base]; l[sp] = lpart[base];
            mx = fmaxf(mx, m[sp]);
        }
        float Wt = 0.f;
        for (int sp = 0; sp < nsp; ++sp) {
            float wv = l[sp] * __expf(m[sp] - mx);
            cf[sp][t] = wv; Wt += wv;
        }
        float inv = 1.0f / Wt;
        for (int sp = 0; sp < nsp; ++sp) cf[sp][t] *= inv;
    }
    __syncthreads();
    size_t rb = ((size_t)(b * 16 + qb)) * 32768;
#pragma unroll
    for (int i = 0; i < 8; ++i) {
        int flat = i * 2048 + t * 8;
        int qi = flat >> 7, dl = flat & 127;
        float acc[8] = {};
        for (int sp = 0; sp < nsp; ++sp) {
            f16x8 v = *(const f16x8*)(Opart + (size_t)sp * 4194304 + rb +
                                      (size_t)qi * 256 + dh * 128 + dl);
            float c = cf[sp][qi];
#pragma unroll
            for (int e = 0; e < 8; ++e) acc[e] += c * (float)v[e];
        }
        f16x8 r;
#pragma unroll
        for (int e = 0; e < 8; ++e) r[e] = (_Float16)acc[e];
        *(f16x8*)(abuf + ((size_t)b * 2048 + qb * 128 + qi) * 256 + dh * 128 + dl) = r;
    }
}

// ---------------------------------------------------------------- launch
extern "C" void kernel_launch(void* const* d_in, const int* in_sizes, int n_in,
                              void* d_out, int out_size, void* d_ws, size_t ws_size,
                              hipStream_t stream) {
    const float* x     = (const float*)d_in[0];
    const float* gamma = (const float*)d_in[1];
    const float* beta  = (const float*)d_in[2];
    const float* Wq    = (const float*)d_in[3];
    const float* bq    = (const float*)d_in[4];
    const float* Wk    = (const float*)d_in[5];
    const float* bk    = (const float*)d_in[6];
    const float* Wv    = (const float*)d_in[7];
    const float* bv    = (const float*)d_in[8];
    const float* Wp    = (const float*)d_in[9];
    const float* bp    = (const float*)d_in[10];
    float* out = (float*)d_out;

    char* ws = (char*)d_ws;
    float* scale = (float*)ws;                     // @0
    float* shift = (float*)(ws + 1024);
    float* bqk   = (float*)(ws + 2048);
    float* mpart = (float*)(ws + 4096);            // up to 1MB
    float* lpart = (float*)(ws + 1052672);         // up to 1MB
    _Float16* wbf   = (_Float16*)(ws + 2101248);   // 512KB: Wq|Wk|Wv|Wp f16
    _Float16* Wvh   = wbf + 131072;
    _Float16* Wph   = wbf + 196608;
    _Float16* ht    = (_Float16*)(ws + 2625536);   // 8MB [8][2048][256]
    _Float16* qkbuf = (_Float16*)(ws + 11014144);  // 16MB [8][2048][512]
    _Float16* vbuf  = (_Float16*)(ws + 27791360);  // 8MB [8][256][2048]
    _Float16* Opart = (_Float16*)(ws + 36179968);  // nsp*4MB [sp][b][qb][128][256]
    _Float16* abuf  = ht;                          // ht dead after v-proj

    int nsp = (ws_size >= (size_t)36179968 + 4u * 8388608u) ? 4 : 2;
    int mspan = 2048 / nsp;

    const long SB = 524288;

    prep_w_kernel<<<1025, 256, 0, stream>>>(Wq, Wk, Wv, Wp, bq, bk, wbf, bqk);
    bn_stats_kernel<<<256, 256, 0, stream>>>(x, gamma, beta, scale, shift);
    norm_t_kernel<<<dim3(32, 4, 8), 256, 0, stream>>>(x, scale, shift, ht);
    gemm_nt<_Float16, false, false><<<dim3(4, 16, 8), 256, 0, stream>>>(
        ht, SB, wbf, 0, bqk, nullptr, 0, qkbuf, 1048576, 2048, 512);
    gemm_nt<_Float16, true, false><<<dim3(16, 2, 8), 256, 0, stream>>>(
        Wvh, 0, ht, SB, bv, nullptr, 0, vbuf, SB, 256, 2048);
    attn2_kernel<<<128 * nsp, 256, 0, stream>>>(qkbuf, vbuf, Opart, mpart, lpart,
                                                nsp, mspan);
    combine2_kernel<<<256, 256, 0, stream>>>(Opart, mpart, lpart, abuf, nsp);
    gemm_nt<float, true, true><<<dim3(16, 2, 8), 256, 0, stream>>>(
        Wph, 0, abuf, SB, bp, x, SB, out, SB, 256, 2048);
}

// Round 5
// 112.556 us; speedup vs baseline: 1.8864x; 1.1330x over previous
//
#include <hip/hip_runtime.h>
#include <hip/hip_fp16.h>

typedef _Float16 f16x8 __attribute__((ext_vector_type(8)));
typedef _Float16 f16x4 __attribute__((ext_vector_type(4)));
typedef float f32x4 __attribute__((ext_vector_type(4)));
typedef float f32x16 __attribute__((ext_vector_type(16)));

#define MFMA16(a, b, c) __builtin_amdgcn_mfma_f32_16x16x32_f16(a, b, c, 0, 0, 0)
#define MFMA32(a, b, c) __builtin_amdgcn_mfma_f32_32x32x16_f16(a, b, c, 0, 0, 0)

__device__ __forceinline__ void gload_lds16(const _Float16* g, void* l) {
    __builtin_amdgcn_global_load_lds(
        (const __attribute__((address_space(1))) void*)g,
        (__attribute__((address_space(3))) void*)l, 16, 0, 0);
}

__device__ __forceinline__ unsigned pkh(float a, float b) {
    typedef __fp16 fp16v2 __attribute__((ext_vector_type(2)));
    fp16v2 h = __builtin_amdgcn_cvt_pkrtz(a, b);
    return __builtin_bit_cast(unsigned, h);
}

__device__ __forceinline__ float fexp2(float x) {
#if __has_builtin(__builtin_amdgcn_exp2f)
    return __builtin_amdgcn_exp2f(x);
#else
    return exp2f(x);
#endif
}

// ---------------------------------------------------------------- prep weights
__global__ __launch_bounds__(256) void prep_w_kernel(
    const float* __restrict__ Wq, const float* __restrict__ Wk,
    const float* __restrict__ Wv, const float* __restrict__ Wp,
    const float* __restrict__ bq, const float* __restrict__ bk,
    _Float16* __restrict__ out, float* __restrict__ bqk)
{
    int bid = blockIdx.x;
    int t = threadIdx.x;
    if (bid == 1024) {
        bqk[t]       = bq[t];
        bqk[256 + t] = bk[t];
        return;
    }
    int i = bid * 256 + t;
    int w = i >> 16, j = i & 65535;
    const float* src = (w == 0) ? Wq : (w == 1) ? Wk : (w == 2) ? Wv : Wp;
    out[i] = (_Float16)src[j];
}

// ---------------------------------------------------------------- BN stats
__global__ __launch_bounds__(256) void bn_stats_kernel(
    const float* __restrict__ x, const float* __restrict__ gamma,
    const float* __restrict__ beta, float* __restrict__ scale,
    float* __restrict__ shift)
{
    int c = blockIdx.x, t = threadIdx.x;
    float s = 0.f, ss = 0.f;
    for (int b = 0; b < 8; ++b) {
        const float* p = x + ((size_t)b * 256 + c) * 2048;
        for (int n = t * 4; n < 2048; n += 1024) {
            float4 v = *(const float4*)(p + n);
            s  += v.x + v.y + v.z + v.w;
            ss += v.x*v.x + v.y*v.y + v.z*v.z + v.w*v.w;
        }
    }
    for (int off = 32; off > 0; off >>= 1) {
        s  += __shfl_down(s,  off, 64);
        ss += __shfl_down(ss, off, 64);
    }
    __shared__ float rs[4], rss[4];
    int w = t >> 6;
    if ((t & 63) == 0) { rs[w] = s; rss[w] = ss; }
    __syncthreads();
    if (t == 0) {
        float S  = rs[0] + rs[1] + rs[2] + rs[3];
        float SS = rss[0] + rss[1] + rss[2] + rss[3];
        float mean = S * (1.f / 16384.f);
        float var  = SS * (1.f / 16384.f) - mean * mean;
        float rstd = rsqrtf(var + 1e-5f);
        float sc = rstd * gamma[c];
        scale[c] = sc;
        shift[c] = beta[c] - mean * sc;
    }
}

// ------------------------------------------- normalize + transpose to [b][n][c]
__global__ __launch_bounds__(256) void norm_t_kernel(
    const float* __restrict__ x, const float* __restrict__ scale,
    const float* __restrict__ shift, _Float16* __restrict__ ht)
{
    __shared__ float tile[64][65];
    int t = threadIdx.x;
    int b = blockIdx.z, c0 = blockIdx.y * 64, n0 = blockIdx.x * 64;
    int nl = t & 63, cq = t >> 6;
#pragma unroll
    for (int r = 0; r < 16; ++r) {
        int cl = cq * 16 + r;
        float v = x[((size_t)b * 256 + c0 + cl) * 2048 + n0 + nl];
        tile[cl][nl] = v * scale[c0 + cl] + shift[c0 + cl];
    }
    __syncthreads();
    int cl2 = t & 63, nq = t >> 6;
#pragma unroll
    for (int r = 0; r < 16; ++r) {
        int nl2 = nq * 16 + r;
        ht[((size_t)b * 2048 + n0 + nl2) * 256 + c0 + cl2] = (_Float16)tile[cl2][nl2];
    }
}

// ---------------------------------------------------------------- NT GEMM (m97-style)
// C[i][j] = sum_k A[i][k]*B[j][k] (+bias, +resid). K=256. BM=128 fixed.
// global_load_lds width-16 staging, double-buffered k-steps.
template<int BN, int WGM, int WGN, typename OT, bool BIAS_I, bool RES>
__global__ __launch_bounds__(256, 3) void gemm_nt(
    const _Float16* __restrict__ Aall, long strideA,
    const _Float16* __restrict__ Ball, long strideB,
    const float* __restrict__ bias,
    const float* __restrict__ resid, long strideR,
    OT* __restrict__ Call, long strideC, int Nn)
{
    constexpr int BM = 128;
    constexpr int WR = BM / WGM;          // wave rows
    constexpr int WC = BN / WGN;          // wave cols
    constexpr int FM = WR / 16, FN = WC / 16;
    constexpr int BUFSZ = 8192 + BN * 64; // A-region 8KB + B-region
    constexpr int NI = 8 + BN / 16;       // staging instrs per k-step
    constexpr int PW = NI / 4;            // per wave

    int b = blockIdx.z;
    const _Float16* A  = Aall + (size_t)b * strideA;
    const _Float16* Bm = Ball + (size_t)b * strideB;
    OT* C = Call + (size_t)b * strideC;
    int i0 = blockIdx.y * BM, j0 = blockIdx.x * BN;

    __shared__ __align__(16) char lds[2 * BUFSZ];

    int t = threadIdx.x, lane = t & 63, w = t >> 6;
    int lr = lane & 15, lg = lane >> 4;
    int wm = w % WGM, wn = w / WGM;

    // per-lane staging source offset within a 16-row chunk (elements)
    int soff = (lane >> 2) * 256 + (lane & 3) * 8;

    f32x4 acc[FM][FN] = {};

    auto stage = [&](int kk, int buf) {
#pragma unroll
        for (int i = 0; i < PW; ++i) {
            int u = w * PW + i;
            if (u < 8)
                gload_lds16(A + (size_t)(i0 + u * 16) * 256 + kk * 32 + soff,
                            lds + buf * BUFSZ + u * 1024);
            else
                gload_lds16(Bm + (size_t)(j0 + (u - 8) * 16) * 256 + kk * 32 + soff,
                            lds + buf * BUFSZ + 8192 + (u - 8) * 1024);
        }
    };

    stage(0, 0);
    __syncthreads();
    int buf = 0;
#pragma unroll
    for (int kk = 0; kk < 8; ++kk) {
        if (kk + 1 < 8) stage(kk + 1, buf ^ 1);
        const char* ab = lds + buf * BUFSZ;
        const char* bb = ab + 8192;
        f16x8 af[FM], bf[FN];
#pragma unroll
        for (int f = 0; f < FM; ++f)
            af[f] = *(const f16x8*)(ab + (wm * WR + f * 16 + lr) * 64 + lg * 16);
#pragma unroll
        for (int f = 0; f < FN; ++f)
            bf[f] = *(const f16x8*)(bb + (wn * WC + f * 16 + lr) * 64 + lg * 16);
        __builtin_amdgcn_s_setprio(1);
#pragma unroll
        for (int fm = 0; fm < FM; ++fm)
#pragma unroll
            for (int fn = 0; fn < FN; ++fn)
                acc[fm][fn] = MFMA16(af[fm], bf[fn], acc[fm][fn]);
        __builtin_amdgcn_s_setprio(0);
        __syncthreads();
        buf ^= 1;
    }
#pragma unroll
    for (int fm = 0; fm < FM; ++fm)
#pragma unroll
        for (int fn = 0; fn < FN; ++fn)
#pragma unroll
            for (int rr = 0; rr < 4; ++rr) {
                int row = i0 + wm * WR + fm * 16 + lg * 4 + rr;
                int col = j0 + wn * WC + fn * 16 + lr;
                float vv = acc[fm][fn][rr] + (BIAS_I ? bias[row] : bias[col]);
                if (RES) vv += resid[(size_t)b * strideR + (size_t)row * Nn + col];
                C[(size_t)row * Nn + col] = (OT)vv;
            }
}

// ---------------------------------------------------------------- flash attention
// 32x32 swapped-QK. qk: [b][n][512] f16; v: [b][c][n] f16. Wave owns 32 q-rows.
// Softmax in base-2 units (Q pre-scaled by log2e/16). Split-KV partials.
__global__ __launch_bounds__(256, 2) void attn2_kernel(
    const _Float16* __restrict__ qk, const _Float16* __restrict__ vb,
    _Float16* __restrict__ Opart, float* __restrict__ mpart,
    float* __restrict__ lpart, int nsp, int mspan)
{
    int id = blockIdx.x;
    int b = id & 7;                       // batch -> XCD affinity
    int rest = id >> 3;
    int qblk = rest & 15, sp = rest >> 4;
    int m_base = sp * mspan;
    int T = mspan >> 5;                   // tiles of 32 m

    __shared__ __align__(16) char lds[66560];

    int t = threadIdx.x, ln = t & 63, w = t >> 6;
    int col = ln & 31, hi = ln >> 5;

    const _Float16* kg = qk + (size_t)b * 1048576 + 256;
    const _Float16* vg = vb + (size_t)b * 524288;

    int koffs[4], voffs[4];
#pragma unroll
    for (int i = 0; i < 4; ++i) {
        int n = w * 4 + i;
        koffs[i] = (ln >> 1) * 512 + (ln & 1) * 8 + n * 16;
        voffs[i] = (((n & 7) * 32 + (ln >> 1)) * 2048) + ((n >> 3) * 16) + (ln & 1) * 8;
    }
    int frd = col * 32 + hi * 16;

    // Q fragments pre-scaled by (1/16)*log2(e): softmax runs in base-2
    f16x8 qf[16];
    {
        const _Float16* qp = qk + ((size_t)b * 2048 + qblk * 128 + w * 32 + col) * 512 + hi * 8;
#pragma unroll
        for (int ks = 0; ks < 16; ++ks) {
            f16x8 v = *(const f16x8*)(qp + ks * 16);
#pragma unroll
            for (int e = 0; e < 8; ++e) v[e] = v[e] * (_Float16)0.09016844f;
            qf[ks] = v;
        }
    }

    f32x16 oacc[8] = {};
    float m_run = -1e30f, l_run = 0.f;

#pragma unroll
    for (int i = 0; i < 4; ++i) {
        int n = w * 4 + i;
        gload_lds16(kg + (size_t)m_base * 512 + koffs[i], lds + n * 1024);
        gload_lds16(vg + m_base + voffs[i], lds + 16384 + n * 1024);
    }
    __syncthreads();

    int buf = 0;
    for (int tt = 0; tt < T; ++tt) {
        if (tt + 1 < T) {
            int m0 = m_base + (tt + 1) * 32;
            char* kb = lds + (buf ^ 1) * 32768;
#pragma unroll
            for (int i = 0; i < 4; ++i) {
                int n = w * 4 + i;
                gload_lds16(kg + (size_t)m0 * 512 + koffs[i], kb + n * 1024);
                gload_lds16(vg + m0 + voffs[i], kb + 16384 + n * 1024);
            }
        }
        const char* kbase = lds + buf * 32768;
        const char* vbase = kbase + 16384;

        // S^T = K Q, two independent accumulation chains
        f32x16 s0 = {}, s1 = {};
        __builtin_amdgcn_s_setprio(1);
#pragma unroll
        for (int ks = 0; ks < 16; ks += 2) {
            f16x8 kf0 = *(const f16x8*)(kbase + ks * 1024 + frd);
            f16x8 kf1 = *(const f16x8*)(kbase + (ks + 1) * 1024 + frd);
            s0 = MFMA32(kf0, qf[ks], s0);
            s1 = MFMA32(kf1, qf[ks + 1], s1);
        }
        __builtin_amdgcn_s_setprio(0);
        f32x16 sacc = s0 + s1;

        // row max: pairwise tree (depth 4) + partner-lane exchange
        float a0 = fmaxf(sacc[0], sacc[8]),  a1 = fmaxf(sacc[1], sacc[9]);
        float a2 = fmaxf(sacc[2], sacc[10]), a3 = fmaxf(sacc[3], sacc[11]);
        float a4 = fmaxf(sacc[4], sacc[12]), a5 = fmaxf(sacc[5], sacc[13]);
        float a6 = fmaxf(sacc[6], sacc[14]), a7 = fmaxf(sacc[7], sacc[15]);
        a0 = fmaxf(a0, a4); a1 = fmaxf(a1, a5); a2 = fmaxf(a2, a6); a3 = fmaxf(a3, a7);
        a0 = fmaxf(a0, a2); a1 = fmaxf(a1, a3);
        float rm = fmaxf(a0, a1);
        rm = fmaxf(rm, __shfl_xor(rm, 32, 64));

        if (__any(rm > m_run + 8.0f)) {          // defer-max (base-2 units)
            float mnew = fmaxf(m_run, rm);
            float alpha = fexp2(m_run - mnew);
            l_run *= alpha;
#pragma unroll
            for (int dt = 0; dt < 8; ++dt) oacc[dt] *= alpha;
            m_run = mnew;
        }

        float pv_[16];
#pragma unroll
        for (int i = 0; i < 16; ++i) pv_[i] = fexp2(sacc[i] - m_run);
        float q0s = (pv_[0] + pv_[8])  + (pv_[1] + pv_[9]);
        float q1s = (pv_[2] + pv_[10]) + (pv_[3] + pv_[11]);
        float q2s = (pv_[4] + pv_[12]) + (pv_[5] + pv_[13]);
        float q3s = (pv_[6] + pv_[14]) + (pv_[7] + pv_[15]);
        float psum = (q0s + q1s) + (q2s + q3s);
        psum += __shfl_xor(psum, 32, 64);
        l_run += psum;

        unsigned W0[2], W1[2], W2[2], W3[2];
        W0[0] = pkh(pv_[0],  pv_[1]);  W0[1] = pkh(pv_[2],  pv_[3]);
        W1[0] = pkh(pv_[4],  pv_[5]);  W1[1] = pkh(pv_[6],  pv_[7]);
        W2[0] = pkh(pv_[8],  pv_[9]);  W2[1] = pkh(pv_[10], pv_[11]);
        W3[0] = pkh(pv_[12], pv_[13]); W3[1] = pkh(pv_[14], pv_[15]);

        __builtin_amdgcn_s_setprio(1);
#pragma unroll
        for (int j = 0; j < 2; ++j) {
            unsigned A0 = j ? W2[0] : W0[0], A1 = j ? W2[1] : W0[1];
            unsigned B0 = j ? W3[0] : W1[0], B1 = j ? W3[1] : W1[1];
            unsigned sx0 = hi ? A0 : B0, sx1 = hi ? A1 : B1;
            unsigned r0 = __shfl_xor(sx0, 32, 64), r1 = __shfl_xor(sx1, 32, 64);
            union { unsigned u[4]; f16x8 v; } pf;
            pf.u[0] = hi ? r0 : A0; pf.u[1] = hi ? r1 : A1;
            pf.u[2] = hi ? B0 : r0; pf.u[3] = hi ? B1 : r1;
#pragma unroll
            for (int dt = 0; dt < 8; ++dt) {
                f16x8 vf = *(const f16x8*)(vbase + j * 8192 + dt * 1024 + frd);
                oacc[dt] = MFMA32(vf, pf.v, oacc[dt]);
            }
        }
        __builtin_amdgcn_s_setprio(0);

        __syncthreads();
        buf ^= 1;
    }

    // epilogue: normalize, transpose via wave-private LDS, coalesced write
    __syncthreads();
    _Float16* tr = (_Float16*)(lds + w * 16640);   // [32 q][260 d-stride]
    float invl = 1.0f / l_run;
#pragma unroll
    for (int dt = 0; dt < 8; ++dt)
#pragma unroll
        for (int g = 0; g < 4; ++g) {
            f16x4 q4;
#pragma unroll
            for (int e = 0; e < 4; ++e) q4[e] = (_Float16)(oacc[dt][g * 4 + e] * invl);
            int d0 = dt * 32 + g * 8 + 4 * hi;
            *(f16x4*)(tr + col * 260 + d0) = q4;
        }
    size_t region = ((size_t)((sp * 8 + b) * 16 + qblk)) * 32768;
    int rrow = ln >> 1, h = ln & 1;
    const _Float16* srcr = tr + rrow * 260 + h * 128;
    _Float16* dstr = Opart + region + (size_t)(w * 32 + rrow) * 256 + h * 128;
#pragma unroll
    for (int i = 0; i < 16; ++i)
        *(f16x8*)(dstr + i * 8) = *(const f16x8*)(srcr + i * 8);

    if (hi == 0) {
        int qi = w * 32 + col;
        int base = ((sp * 8 + b) * 16 + qblk) * 128 + qi;
        mpart[base] = m_run;
        lpart[base] = l_run;
    }
}

// ---------------------------------------------------------------- split combine
__global__ __launch_bounds__(256) void combine2_kernel(
    const _Float16* __restrict__ Opart, const float* __restrict__ mpart,
    const float* __restrict__ lpart, _Float16* __restrict__ abuf, int nsp)
{
    int id = blockIdx.x;
    int b = id & 7, qb = (id >> 3) & 15, dh = id >> 7;
    int t = threadIdx.x;
    __shared__ float cf[4][128];
    if (t < 128) {
        float m[4], l[4], mx = -1e30f;
        for (int sp = 0; sp < nsp; ++sp) {
            int base = ((sp * 8 + b) * 16 + qb) * 128 + t;
            m[sp] = mpart[base]; l[sp] = lpart[base];
            mx = fmaxf(mx, m[sp]);
        }
        float Wt = 0.f;
        for (int sp = 0; sp < nsp; ++sp) {
            float wv = l[sp] * fexp2(m[sp] - mx);   // base-2 units
            cf[sp][t] = wv; Wt += wv;
        }
        float inv = 1.0f / Wt;
        for (int sp = 0; sp < nsp; ++sp) cf[sp][t] *= inv;
    }
    __syncthreads();
    size_t rb = ((size_t)(b * 16 + qb)) * 32768;
#pragma unroll
    for (int i = 0; i < 8; ++i) {
        int flat = i * 2048 + t * 8;
        int qi = flat >> 7, dl = flat & 127;
        float acc[8] = {};
        for (int sp = 0; sp < nsp; ++sp) {
            f16x8 v = *(const f16x8*)(Opart + (size_t)sp * 4194304 + rb +
                                      (size_t)qi * 256 + dh * 128 + dl);
            float c = cf[sp][qi];
#pragma unroll
            for (int e = 0; e < 8; ++e) acc[e] += c * (float)v[e];
        }
        f16x8 r;
#pragma unroll
        for (int e = 0; e < 8; ++e) r[e] = (_Float16)acc[e];
        *(f16x8*)(abuf + ((size_t)b * 2048 + qb * 128 + qi) * 256 + dh * 128 + dl) = r;
    }
}

// ---------------------------------------------------------------- launch
extern "C" void kernel_launch(void* const* d_in, const int* in_sizes, int n_in,
                              void* d_out, int out_size, void* d_ws, size_t ws_size,
                              hipStream_t stream) {
    const float* x     = (const float*)d_in[0];
    const float* gamma = (const float*)d_in[1];
    const float* beta  = (const float*)d_in[2];
    const float* Wq    = (const float*)d_in[3];
    const float* bq    = (const float*)d_in[4];
    const float* Wk    = (const float*)d_in[5];
    const float* bk    = (const float*)d_in[6];
    const float* Wv    = (const float*)d_in[7];
    const float* bv    = (const float*)d_in[8];
    const float* Wp    = (const float*)d_in[9];
    const float* bp    = (const float*)d_in[10];
    float* out = (float*)d_out;

    char* ws = (char*)d_ws;
    float* scale = (float*)ws;
    float* shift = (float*)(ws + 1024);
    float* bqk   = (float*)(ws + 2048);
    float* mpart = (float*)(ws + 4096);
    float* lpart = (float*)(ws + 1052672);
    _Float16* wbf   = (_Float16*)(ws + 2101248);   // 512KB: Wq|Wk|Wv|Wp f16
    _Float16* Wvh   = wbf + 131072;
    _Float16* Wph   = wbf + 196608;
    _Float16* ht    = (_Float16*)(ws + 2625536);   // 8MB [8][2048][256]
    _Float16* qkbuf = (_Float16*)(ws + 11014144);  // 16MB [8][2048][512]
    _Float16* vbuf  = (_Float16*)(ws + 27791360);  // 8MB [8][256][2048]
    _Float16* Opart = (_Float16*)(ws + 36179968);  // nsp*4MB
    _Float16* abuf  = ht;

    int nsp = (ws_size >= (size_t)36179968 + 4u * 8388608u) ? 4 : 2;
    int mspan = 2048 / nsp;

    const long SB = 524288;

    prep_w_kernel<<<1025, 256, 0, stream>>>(Wq, Wk, Wv, Wp, bq, bk, wbf, bqk);
    bn_stats_kernel<<<256, 256, 0, stream>>>(x, gamma, beta, scale, shift);
    norm_t_kernel<<<dim3(32, 4, 8), 256, 0, stream>>>(x, scale, shift, ht);
    // qk: [b][n][512] = ht . [Wq;Wk]^T  (tile 128x128, 512 blocks)
    gemm_nt<128, 2, 2, _Float16, false, false><<<dim3(4, 16, 8), 256, 0, stream>>>(
        ht, SB, wbf, 0, bqk, nullptr, 0, qkbuf, 1048576, 512);
    // v: [b][o][n] = Wv . ht^T  (tile 128x64, 512 blocks)
    gemm_nt<64, 4, 1, _Float16, true, false><<<dim3(32, 2, 8), 256, 0, stream>>>(
        Wvh, 0, ht, SB, bv, nullptr, 0, vbuf, SB, 2048);
    attn2_kernel<<<128 * nsp, 256, 0, stream>>>(qkbuf, vbuf, Opart, mpart, lpart,
                                                nsp, mspan);
    combine2_kernel<<<256, 256, 0, stream>>>(Opart, mpart, lpart, abuf, nsp);
    // out: [b][o][n] = Wp . attn^T + bp + x
    gemm_nt<64, 4, 1, float, true, true><<<dim3(32, 2, 8), 256, 0, stream>>>(
        Wph, 0, abuf, SB, bp, x, SB, out, SB, 2048);
}

// Round 6
// 112.070 us; speedup vs baseline: 1.8945x; 1.0043x over previous
//
#include <hip/hip_runtime.h>
#include <hip/hip_fp16.h>

typedef _Float16 f16x8 __attribute__((ext_vector_type(8)));
typedef _Float16 f16x4 __attribute__((ext_vector_type(4)));
typedef float f32x4 __attribute__((ext_vector_type(4)));
typedef float f32x16 __attribute__((ext_vector_type(16)));

#define MFMA16(a, b, c) __builtin_amdgcn_mfma_f32_16x16x32_f16(a, b, c, 0, 0, 0)
#define MFMA32(a, b, c) __builtin_amdgcn_mfma_f32_32x32x16_f16(a, b, c, 0, 0, 0)

__device__ __forceinline__ void gload_lds16(const _Float16* g, void* l) {
    __builtin_amdgcn_global_load_lds(
        (const __attribute__((address_space(1))) void*)g,
        (__attribute__((address_space(3))) void*)l, 16, 0, 0);
}

__device__ __forceinline__ unsigned pkh(float a, float b) {
    typedef __fp16 fp16v2 __attribute__((ext_vector_type(2)));
    fp16v2 h = __builtin_amdgcn_cvt_pkrtz(a, b);
    return __builtin_bit_cast(unsigned, h);
}

__device__ __forceinline__ float fexp2(float x) {
#if __has_builtin(__builtin_amdgcn_exp2f)
    return __builtin_amdgcn_exp2f(x);
#else
    return exp2f(x);
#endif
}

// ---------------------------------------------------------------- prep weights
__global__ __launch_bounds__(256) void prep_w_kernel(
    const float* __restrict__ Wq, const float* __restrict__ Wk,
    const float* __restrict__ Wv, const float* __restrict__ Wp,
    const float* __restrict__ bq, const float* __restrict__ bk,
    _Float16* __restrict__ out, float* __restrict__ bqk)
{
    int bid = blockIdx.x;
    int t = threadIdx.x;
    if (bid == 1024) {
        bqk[t]       = bq[t];
        bqk[256 + t] = bk[t];
        return;
    }
    int i = bid * 256 + t;
    int w = i >> 16, j = i & 65535;
    const float* src = (w == 0) ? Wq : (w == 1) ? Wk : (w == 2) ? Wv : Wp;
    out[i] = (_Float16)src[j];
}

// ---------------------------------------------------------------- BN stats
__global__ __launch_bounds__(256) void bn_stats_kernel(
    const float* __restrict__ x, const float* __restrict__ gamma,
    const float* __restrict__ beta, float* __restrict__ scale,
    float* __restrict__ shift)
{
    int c = blockIdx.x, t = threadIdx.x;
    float s = 0.f, ss = 0.f;
    for (int b = 0; b < 8; ++b) {
        const float* p = x + ((size_t)b * 256 + c) * 2048;
        for (int n = t * 4; n < 2048; n += 1024) {
            float4 v = *(const float4*)(p + n);
            s  += v.x + v.y + v.z + v.w;
            ss += v.x*v.x + v.y*v.y + v.z*v.z + v.w*v.w;
        }
    }
    for (int off = 32; off > 0; off >>= 1) {
        s  += __shfl_down(s,  off, 64);
        ss += __shfl_down(ss, off, 64);
    }
    __shared__ float rs[4], rss[4];
    int w = t >> 6;
    if ((t & 63) == 0) { rs[w] = s; rss[w] = ss; }
    __syncthreads();
    if (t == 0) {
        float S  = rs[0] + rs[1] + rs[2] + rs[3];
        float SS = rss[0] + rss[1] + rss[2] + rss[3];
        float mean = S * (1.f / 16384.f);
        float var  = SS * (1.f / 16384.f) - mean * mean;
        float rstd = rsqrtf(var + 1e-5f);
        float sc = rstd * gamma[c];
        scale[c] = sc;
        shift[c] = beta[c] - mean * sc;
    }
}

// ------------------------------------------- normalize + transpose to [b][n][c]
__global__ __launch_bounds__(256) void norm_t_kernel(
    const float* __restrict__ x, const float* __restrict__ scale,
    const float* __restrict__ shift, _Float16* __restrict__ ht)
{
    __shared__ float tile[64][65];
    int t = threadIdx.x;
    int b = blockIdx.z, c0 = blockIdx.y * 64, n0 = blockIdx.x * 64;
    int nl = t & 63, cq = t >> 6;
#pragma unroll
    for (int r = 0; r < 16; ++r) {
        int cl = cq * 16 + r;
        float v = x[((size_t)b * 256 + c0 + cl) * 2048 + n0 + nl];
        tile[cl][nl] = v * scale[c0 + cl] + shift[c0 + cl];
    }
    __syncthreads();
    int cl2 = t & 63, nq = t >> 6;
#pragma unroll
    for (int r = 0; r < 16; ++r) {
        int nl2 = nq * 16 + r;
        ht[((size_t)b * 2048 + n0 + nl2) * 256 + c0 + cl2] = (_Float16)tile[cl2][nl2];
    }
}

// ---------------------------------------------------------------- NT GEMM (m97-style)
// C[i][j] = sum_k A[i][k]*B[j][k] (+bias, +resid). K=256. BM=128 fixed.
// LDS 16B units XOR-swizzled within each 1KB chunk: unit(row,g)=row*4+(g^((row>>1)&3)).
template<int BN, int WGM, int WGN, typename OT, bool BIAS_I, bool RES>
__global__ __launch_bounds__(256, 3) void gemm_nt(
    const _Float16* __restrict__ Aall, long strideA,
    const _Float16* __restrict__ Ball, long strideB,
    const float* __restrict__ bias,
    const float* __restrict__ resid, long strideR,
    OT* __restrict__ Call, long strideC, int Nn)
{
    constexpr int BM = 128;
    constexpr int WR = BM / WGM;
    constexpr int WC = BN / WGN;
    constexpr int FM = WR / 16, FN = WC / 16;
    constexpr int BUFSZ = 8192 + BN * 64;
    constexpr int NI = 8 + BN / 16;
    constexpr int PW = NI / 4;

    int b = blockIdx.z;
    const _Float16* A  = Aall + (size_t)b * strideA;
    const _Float16* Bm = Ball + (size_t)b * strideB;
    OT* C = Call + (size_t)b * strideC;
    int i0 = blockIdx.y * BM, j0 = blockIdx.x * BN;

    __shared__ __align__(16) char lds[2 * BUFSZ];

    int t = threadIdx.x, lane = t & 63, w = t >> 6;
    int lr = lane & 15, lg = lane >> 4;
    int wm = w % WGM, wn = w / WGM;

    // staging source offset: dest unit d=lane holds (row=d>>2, g=(d&3)^((d>>3)&3))
    int soff = (lane >> 2) * 256 + (((lane & 3) ^ ((lane >> 3) & 3))) * 8;
    // fragment read k-group offset (lane-constant XOR)
    int lgx16 = ((lg ^ ((lr >> 1) & 3))) * 16;

    f32x4 acc[FM][FN] = {};

    auto stage = [&](int kk, int buf) {
#pragma unroll
        for (int i = 0; i < PW; ++i) {
            int u = w * PW + i;
            if (u < 8)
                gload_lds16(A + (size_t)(i0 + u * 16) * 256 + kk * 32 + soff,
                            lds + buf * BUFSZ + u * 1024);
            else
                gload_lds16(Bm + (size_t)(j0 + (u - 8) * 16) * 256 + kk * 32 + soff,
                            lds + buf * BUFSZ + 8192 + (u - 8) * 1024);
        }
    };

    stage(0, 0);
    __syncthreads();
    int buf = 0;
#pragma unroll
    for (int kk = 0; kk < 8; ++kk) {
        if (kk + 1 < 8) stage(kk + 1, buf ^ 1);
        const char* ab = lds + buf * BUFSZ;
        const char* bb = ab + 8192;
        f16x8 af[FM], bf[FN];
#pragma unroll
        for (int f = 0; f < FM; ++f)
            af[f] = *(const f16x8*)(ab + (wm * WR + f * 16 + lr) * 64 + lgx16);
#pragma unroll
        for (int f = 0; f < FN; ++f)
            bf[f] = *(const f16x8*)(bb + (wn * WC + f * 16 + lr) * 64 + lgx16);
        __builtin_amdgcn_s_setprio(1);
#pragma unroll
        for (int fm = 0; fm < FM; ++fm)
#pragma unroll
            for (int fn = 0; fn < FN; ++fn)
                acc[fm][fn] = MFMA16(af[fm], bf[fn], acc[fm][fn]);
        __builtin_amdgcn_s_setprio(0);
        __syncthreads();
        buf ^= 1;
    }
#pragma unroll
    for (int fm = 0; fm < FM; ++fm)
#pragma unroll
        for (int fn = 0; fn < FN; ++fn)
#pragma unroll
            for (int rr = 0; rr < 4; ++rr) {
                int row = i0 + wm * WR + fm * 16 + lg * 4 + rr;
                int col = j0 + wn * WC + fn * 16 + lr;
                float vv = acc[fm][fn][rr] + (BIAS_I ? bias[row] : bias[col]);
                if (RES) vv += resid[(size_t)b * strideR + (size_t)row * Nn + col];
                C[(size_t)row * Nn + col] = (OT)vv;
            }
}

// ---------------------------------------------------------------- flash attention
// 32x32 swapped-QK. qk: [b][n][512] f16; v: [b][c][n] f16. Wave owns 32 q-rows.
// K/V LDS 16B units XOR-swizzled per 1KB chunk: unit(m,h)=m*2+(h^((m>>2)&1)).
__global__ __launch_bounds__(256, 2) void attn2_kernel(
    const _Float16* __restrict__ qk, const _Float16* __restrict__ vb,
    _Float16* __restrict__ Opart, float* __restrict__ mpart,
    float* __restrict__ lpart, int nsp, int mspan)
{
    int id = blockIdx.x;
    int b = id & 7;                       // batch -> XCD affinity
    int rest = id >> 3;
    int qblk = rest & 15, sp = rest >> 4;
    int m_base = sp * mspan;
    int T = mspan >> 5;                   // tiles of 32 m

    __shared__ __align__(16) char lds[66560];

    int t = threadIdx.x, ln = t & 63, w = t >> 6;
    int col = ln & 31, hi = ln >> 5;

    const _Float16* kg = qk + (size_t)b * 1048576 + 256;
    const _Float16* vg = vb + (size_t)b * 524288;

    // staging: dest unit d=ln holds (m=d>>1, h=(d&1)^((d>>3)&1))
    int hsw = ((ln & 1) ^ ((ln >> 3) & 1));
    int koffs[4], voffs[4];
#pragma unroll
    for (int i = 0; i < 4; ++i) {
        int n = w * 4 + i;
        koffs[i] = (ln >> 1) * 512 + hsw * 8 + n * 16;
        voffs[i] = (((n & 7) * 32 + (ln >> 1)) * 2048) + ((n >> 3) * 16) + hsw * 8;
    }
    // fragment read byte offset with matching swizzle (lane-constant)
    int frd = col * 32 + ((hi ^ ((col >> 2) & 1))) * 16;

    // Q fragments pre-scaled by (1/16)*log2(e): softmax runs in base-2
    f16x8 qf[16];
    {
        const _Float16* qp = qk + ((size_t)b * 2048 + qblk * 128 + w * 32 + col) * 512 + hi * 8;
#pragma unroll
        for (int ks = 0; ks < 16; ++ks) {
            f16x8 v = *(const f16x8*)(qp + ks * 16);
#pragma unroll
            for (int e = 0; e < 8; ++e) v[e] = v[e] * (_Float16)0.09016844f;
            qf[ks] = v;
        }
    }

    f32x16 oacc[8] = {};
    float m_run = -1e30f, l_run = 0.f;

#pragma unroll
    for (int i = 0; i < 4; ++i) {
        int n = w * 4 + i;
        gload_lds16(kg + (size_t)m_base * 512 + koffs[i], lds + n * 1024);
        gload_lds16(vg + m_base + voffs[i], lds + 16384 + n * 1024);
    }
    __syncthreads();

    int buf = 0;
    for (int tt = 0; tt < T; ++tt) {
        if (tt + 1 < T) {
            int m0 = m_base + (tt + 1) * 32;
            char* kb = lds + (buf ^ 1) * 32768;
#pragma unroll
            for (int i = 0; i < 4; ++i) {
                int n = w * 4 + i;
                gload_lds16(kg + (size_t)m0 * 512 + koffs[i], kb + n * 1024);
                gload_lds16(vg + m0 + voffs[i], kb + 16384 + n * 1024);
            }
        }
        const char* kbase = lds + buf * 32768;
        const char* vbase = kbase + 16384;

        // S^T = K Q, two independent accumulation chains
        f32x16 s0 = {}, s1 = {};
        __builtin_amdgcn_s_setprio(1);
#pragma unroll
        for (int ks = 0; ks < 16; ks += 2) {
            f16x8 kf0 = *(const f16x8*)(kbase + ks * 1024 + frd);
            f16x8 kf1 = *(const f16x8*)(kbase + (ks + 1) * 1024 + frd);
            s0 = MFMA32(kf0, qf[ks], s0);
            s1 = MFMA32(kf1, qf[ks + 1], s1);
        }
        __builtin_amdgcn_s_setprio(0);
        f32x16 sacc = s0 + s1;

        // row max: pairwise tree + partner-lane exchange
        float a0 = fmaxf(sacc[0], sacc[8]),  a1 = fmaxf(sacc[1], sacc[9]);
        float a2 = fmaxf(sacc[2], sacc[10]), a3 = fmaxf(sacc[3], sacc[11]);
        float a4 = fmaxf(sacc[4], sacc[12]), a5 = fmaxf(sacc[5], sacc[13]);
        float a6 = fmaxf(sacc[6], sacc[14]), a7 = fmaxf(sacc[7], sacc[15]);
        a0 = fmaxf(a0, a4); a1 = fmaxf(a1, a5); a2 = fmaxf(a2, a6); a3 = fmaxf(a3, a7);
        a0 = fmaxf(a0, a2); a1 = fmaxf(a1, a3);
        float rm = fmaxf(a0, a1);
        rm = fmaxf(rm, __shfl_xor(rm, 32, 64));

        if (__any(rm > m_run + 8.0f)) {          // defer-max (base-2 units)
            float mnew = fmaxf(m_run, rm);
            float alpha = fexp2(m_run - mnew);
            l_run *= alpha;
#pragma unroll
            for (int dt = 0; dt < 8; ++dt) oacc[dt] *= alpha;
            m_run = mnew;
        }

        float pv_[16];
#pragma unroll
        for (int i = 0; i < 16; ++i) pv_[i] = fexp2(sacc[i] - m_run);
        float q0s = (pv_[0] + pv_[8])  + (pv_[1] + pv_[9]);
        float q1s = (pv_[2] + pv_[10]) + (pv_[3] + pv_[11]);
        float q2s = (pv_[4] + pv_[12]) + (pv_[5] + pv_[13]);
        float q3s = (pv_[6] + pv_[14]) + (pv_[7] + pv_[15]);
        float psum = (q0s + q1s) + (q2s + q3s);
        psum += __shfl_xor(psum, 32, 64);
        l_run += psum;

        unsigned W0[2], W1[2], W2[2], W3[2];
        W0[0] = pkh(pv_[0],  pv_[1]);  W0[1] = pkh(pv_[2],  pv_[3]);
        W1[0] = pkh(pv_[4],  pv_[5]);  W1[1] = pkh(pv_[6],  pv_[7]);
        W2[0] = pkh(pv_[8],  pv_[9]);  W2[1] = pkh(pv_[10], pv_[11]);
        W3[0] = pkh(pv_[12], pv_[13]); W3[1] = pkh(pv_[14], pv_[15]);

        __builtin_amdgcn_s_setprio(1);
#pragma unroll
        for (int j = 0; j < 2; ++j) {
            unsigned A0 = j ? W2[0] : W0[0], A1 = j ? W2[1] : W0[1];
            unsigned B0 = j ? W3[0] : W1[0], B1 = j ? W3[1] : W1[1];
            unsigned sx0 = hi ? A0 : B0, sx1 = hi ? A1 : B1;
            unsigned r0 = __shfl_xor(sx0, 32, 64), r1 = __shfl_xor(sx1, 32, 64);
            union { unsigned u[4]; f16x8 v; } pf;
            pf.u[0] = hi ? r0 : A0; pf.u[1] = hi ? r1 : A1;
            pf.u[2] = hi ? B0 : r0; pf.u[3] = hi ? B1 : r1;
#pragma unroll
            for (int dt = 0; dt < 8; ++dt) {
                f16x8 vf = *(const f16x8*)(vbase + j * 8192 + dt * 1024 + frd);
                oacc[dt] = MFMA32(vf, pf.v, oacc[dt]);
            }
        }
        __builtin_amdgcn_s_setprio(0);

        __syncthreads();
        buf ^= 1;
    }

    // epilogue: normalize, transpose via wave-private LDS, coalesced write
    __syncthreads();
    _Float16* tr = (_Float16*)(lds + w * 16640);   // [32 q][260 d-stride]
    float invl = 1.0f / l_run;
#pragma unroll
    for (int dt = 0; dt < 8; ++dt)
#pragma unroll
        for (int g = 0; g < 4; ++g) {
            f16x4 q4;
#pragma unroll
            for (int e = 0; e < 4; ++e) q4[e] = (_Float16)(oacc[dt][g * 4 + e] * invl);
            int d0 = dt * 32 + g * 8 + 4 * hi;
            *(f16x4*)(tr + col * 260 + d0) = q4;
        }
    size_t region = ((size_t)((sp * 8 + b) * 16 + qblk)) * 32768;
    int rrow = ln >> 1, h = ln & 1;
    const _Float16* srcr = tr + rrow * 260 + h * 128;
    _Float16* dstr = Opart + region + (size_t)(w * 32 + rrow) * 256 + h * 128;
#pragma unroll
    for (int i = 0; i < 16; ++i)
        *(f16x8*)(dstr + i * 8) = *(const f16x8*)(srcr + i * 8);

    if (hi == 0) {
        int qi = w * 32 + col;
        int base = ((sp * 8 + b) * 16 + qblk) * 128 + qi;
        mpart[base] = m_run;
        lpart[base] = l_run;
    }
}

// ---------------------------------------------------------------- split combine
__global__ __launch_bounds__(256) void combine2_kernel(
    const _Float16* __restrict__ Opart, const float* __restrict__ mpart,
    const float* __restrict__ lpart, _Float16* __restrict__ abuf, int nsp)
{
    int id = blockIdx.x;
    int b = id & 7, qb = (id >> 3) & 15, dh = id >> 7;
    int t = threadIdx.x;
    __shared__ float cf[4][128];
    if (t < 128) {
        float m[4], l[4], mx = -1e30f;
        for (int sp = 0; sp < nsp; ++sp) {
            int base = ((sp * 8 + b) * 16 + qb) * 128 + t;
            m[sp] = mpart[base]; l[sp] = lpart[base];
            mx = fmaxf(mx, m[sp]);
        }
        float Wt = 0.f;
        for (int sp = 0; sp < nsp; ++sp) {
            float wv = l[sp] * fexp2(m[sp] - mx);   // base-2 units
            cf[sp][t] = wv; Wt += wv;
        }
        float inv = 1.0f / Wt;
        for (int sp = 0; sp < nsp; ++sp) cf[sp][t] *= inv;
    }
    __syncthreads();
    size_t rb = ((size_t)(b * 16 + qb)) * 32768;
#pragma unroll
    for (int i = 0; i < 8; ++i) {
        int flat = i * 2048 + t * 8;
        int qi = flat >> 7, dl = flat & 127;
        float acc[8] = {};
        for (int sp = 0; sp < nsp; ++sp) {
            f16x8 v = *(const f16x8*)(Opart + (size_t)sp * 4194304 + rb +
                                      (size_t)qi * 256 + dh * 128 + dl);
            float c = cf[sp][qi];
#pragma unroll
            for (int e = 0; e < 8; ++e) acc[e] += c * (float)v[e];
        }
        f16x8 r;
#pragma unroll
        for (int e = 0; e < 8; ++e) r[e] = (_Float16)acc[e];
        *(f16x8*)(abuf + ((size_t)b * 2048 + qb * 128 + qi) * 256 + dh * 128 + dl) = r;
    }
}

// ---------------------------------------------------------------- launch
extern "C" void kernel_launch(void* const* d_in, const int* in_sizes, int n_in,
                              void* d_out, int out_size, void* d_ws, size_t ws_size,
                              hipStream_t stream) {
    const float* x     = (const float*)d_in[0];
    const float* gamma = (const float*)d_in[1];
    const float* beta  = (const float*)d_in[2];
    const float* Wq    = (const float*)d_in[3];
    const float* bq    = (const float*)d_in[4];
    const float* Wk    = (const float*)d_in[5];
    const float* bk    = (const float*)d_in[6];
    const float* Wv    = (const float*)d_in[7];
    const float* bv    = (const float*)d_in[8];
    const float* Wp    = (const float*)d_in[9];
    const float* bp    = (const float*)d_in[10];
    float* out = (float*)d_out;

    char* ws = (char*)d_ws;
    float* scale = (float*)ws;
    float* shift = (float*)(ws + 1024);
    float* bqk   = (float*)(ws + 2048);
    float* mpart = (float*)(ws + 4096);
    float* lpart = (float*)(ws + 1052672);
    _Float16* wbf   = (_Float16*)(ws + 2101248);   // 512KB: Wq|Wk|Wv|Wp f16
    _Float16* Wvh   = wbf + 131072;
    _Float16* Wph   = wbf + 196608;
    _Float16* ht    = (_Float16*)(ws + 2625536);   // 8MB [8][2048][256]
    _Float16* qkbuf = (_Float16*)(ws + 11014144);  // 16MB [8][2048][512]
    _Float16* vbuf  = (_Float16*)(ws + 27791360);  // 8MB [8][256][2048]
    _Float16* Opart = (_Float16*)(ws + 36179968);  // nsp*4MB
    _Float16* abuf  = ht;

    int nsp = (ws_size >= (size_t)36179968 + 4u * 8388608u) ? 4 : 2;
    int mspan = 2048 / nsp;

    const long SB = 524288;

    prep_w_kernel<<<1025, 256, 0, stream>>>(Wq, Wk, Wv, Wp, bq, bk, wbf, bqk);
    bn_stats_kernel<<<256, 256, 0, stream>>>(x, gamma, beta, scale, shift);
    norm_t_kernel<<<dim3(32, 4, 8), 256, 0, stream>>>(x, scale, shift, ht);
    // qk: [b][n][512] = ht . [Wq;Wk]^T  (tile 128x128, 512 blocks)
    gemm_nt<128, 2, 2, _Float16, false, false><<<dim3(4, 16, 8), 256, 0, stream>>>(
        ht, SB, wbf, 0, bqk, nullptr, 0, qkbuf, 1048576, 512);
    // v: [b][o][n] = Wv . ht^T  (tile 128x64, 512 blocks)
    gemm_nt<64, 4, 1, _Float16, true, false><<<dim3(32, 2, 8), 256, 0, stream>>>(
        Wvh, 0, ht, SB, bv, nullptr, 0, vbuf, SB, 2048);
    attn2_kernel<<<128 * nsp, 256, 0, stream>>>(qkbuf, vbuf, Opart, mpart, lpart,
                                                nsp, mspan);
    combine2_kernel<<<256, 256, 0, stream>>>(Opart, mpart, lpart, abuf, nsp);
    // out: [b][o][n] = Wp . attn^T + bp + x
    gemm_nt<64, 4, 1, float, true, true><<<dim3(32, 2, 8), 256, 0, stream>>>(
        Wph, 0, abuf, SB, bp, x, SB, out, SB, 2048);
}